// Round 6
// baseline (184.886 us; speedup 1.0000x reference)
//
#include <hip/hip_runtime.h>
#include <math.h>

#define NCLUST 512
#define DPER 32
#define NFEAT 1024
#define NSAMP (NCLUST * DPER)   // 16384
#define ALPHA_C 1.0f
#define EPS_C 1e-8f
#define MARGIN_C 0.25f

#define GBM 128
#define GBN 128
#define GBK 32
#define NCHUNK 8   // 512 cols / 64-col wave chunks

typedef __attribute__((ext_vector_type(4))) float f32x4;
typedef __attribute__((ext_vector_type(8))) _Float16 f16x8;

__device__ __forceinline__ unsigned f2h(float f) {
  _Float16 h = (_Float16)f;
  return (unsigned)__builtin_bit_cast(ushort, h);
}

__device__ __forceinline__ void gload16(const ushort* g, ushort* l) {
  __builtin_amdgcn_global_load_lds(
      (const __attribute__((address_space(1))) unsigned int*)g,
      (__attribute__((address_space(3))) unsigned int*)l, 16, 0, 0);
}

// ---------------- Kernel PRE: means, c2, ccls, Bf16, Af16, r2, intra --------
// Block = cluster. Pass 1: stream 32x1024 block (HBM), accumulate mean + r2,
// write Af16. Pass 2: re-read (L2-hot) for intra dot with mean.
__global__ __launch_bounds__(256) void k_pre(const float* __restrict__ inp,
                                             const int* __restrict__ target,
                                             float* __restrict__ means,
                                             ushort* __restrict__ Bf16,
                                             ushort* __restrict__ Af16,
                                             float* __restrict__ c2,
                                             float* __restrict__ r2,
                                             float* __restrict__ intra,
                                             int* __restrict__ ccls,
                                             int* __restrict__ wcount) {
  const int m = blockIdx.x;
  const int t = threadIdx.x;
  const int w = t >> 6, l = t & 63;
  __shared__ float redA[DPER][4];
  __shared__ float redB[DPER][4];
  __shared__ float red4[4];
  __shared__ float c2s;
  const float* base = inp + (size_t)m * DPER * NFEAT + t * 4;
  ushort* abase = Af16 + (size_t)m * DPER * NFEAT + t * 4;

  float sx = 0.f, sy = 0.f, sz = 0.f, sw = 0.f;
  for (int d = 0; d < DPER; ++d) {
    float4 v = *(const float4*)(base + (size_t)d * NFEAT);
    sx += v.x; sy += v.y; sz += v.z; sw += v.w;
    uint2 hw;
    hw.x = f2h(v.x) | (f2h(v.y) << 16);
    hw.y = f2h(v.z) | (f2h(v.w) << 16);
    *(uint2*)(abase + (size_t)d * NFEAT) = hw;
    float p = v.x * v.x + v.y * v.y + v.z * v.z + v.w * v.w;
    #pragma unroll
    for (int off = 32; off; off >>= 1) p += __shfl_down(p, off);
    if (l == 0) redA[d][w] = p;
  }
  // mean of this cluster (4 cols per thread)
  const float inv = 1.0f / 32.0f;
  sx *= inv; sy *= inv; sz *= inv; sw *= inv;
  *(float4*)(means + (size_t)m * NFEAT + t * 4) = make_float4(sx, sy, sz, sw);
  uint2 bw;
  bw.x = f2h(sx) | (f2h(sy) << 16);
  bw.y = f2h(sz) | (f2h(sw) << 16);
  *(uint2*)&Bf16[(size_t)m * NFEAT + t * 4] = bw;
  float sq = sx * sx + sy * sy + sz * sz + sw * sw;
  #pragma unroll
  for (int off = 32; off; off >>= 1) sq += __shfl_down(sq, off);
  if (l == 0) red4[w] = sq;
  __syncthreads();
  float rr = 0.f;
  if (t < DPER) {
    rr = redA[t][0] + redA[t][1] + redA[t][2] + redA[t][3];
    r2[m * DPER + t] = rr;
  }
  if (t == 0) {
    float cc = red4[0] + red4[1] + red4[2] + red4[3];
    c2s = cc;
    c2[m] = cc;
    ccls[m] = target[m * DPER];
    if (m == 0) *wcount = 0;   // reset worklist counter each call
  }
  __syncthreads();
  const float c2v = c2s;
  // pass 2: intra dot (L2-hot re-read)
  for (int d = 0; d < DPER; ++d) {
    float4 v = *(const float4*)(base + (size_t)d * NFEAT);
    float p = v.x * sx + v.y * sy + v.z * sz + v.w * sw;
    #pragma unroll
    for (int off = 32; off; off >>= 1) p += __shfl_down(p, off);
    if (l == 0) redB[d][w] = p;
  }
  __syncthreads();
  if (t < DPER) {
    float dot = redB[t][0] + redB[t][1] + redB[t][2] + redB[t][3];
    intra[m * DPER + t] = rr + c2v - 2.0f * dot;
  }
}

// ---------------- Kernel D: variance -> var_norm ----------------
__global__ __launch_bounds__(256) void k_var(const float* __restrict__ intra,
                                             float* __restrict__ vn) {
  const int t = threadIdx.x;
  float s = 0.f;
  for (int i = t; i < NSAMP; i += 256) s += intra[i];
  __shared__ float red[4];
  #pragma unroll
  for (int off = 32; off > 0; off >>= 1) s += __shfl_down(s, off);
  if ((t & 63) == 0) red[t >> 6] = s;
  __syncthreads();
  if (t == 0) {
    float tot = red[0] + red[1] + red[2] + red[3];
    float var = tot / (float)(NSAMP - 1);
    vn[0] = -1.0f / (2.0f * var * var);
  }
}

// ---------------- Kernel E: f16 MFMA GEMM (m97 template) + epilogue ----------
// 128x128x32 tile, 4 waves (2x2), wave tile 64x64, global_load_lds staging,
// XOR chunk swizzle. Grid 512 = 128 rowblks x 4 colblks, XCD-swizzled.
__global__ __launch_bounds__(256, 3) void k_gemm(
    const ushort* __restrict__ Af16, const ushort* __restrict__ Bf16,
    const float* __restrict__ c2, const float* __restrict__ r2,
    const float* __restrict__ vnp, const int* __restrict__ ccls,
    const int* __restrict__ target,
    float* __restrict__ den_p, float* __restrict__ minv_p,
    float* __restrict__ minv2_p, float* __restrict__ minc_p) {
  __shared__ ushort As[GBM * GBK];   // 8 KiB
  __shared__ ushort Bs[GBN * GBK];   // 8 KiB
  const int t = threadIdx.x;
  const int l = t & 63, w = t >> 6;
  const int wg = (blockIdx.x & 7) * 64 + (blockIdx.x >> 3);  // bijective (512%8==0)
  const int rowblk = wg >> 2, colblk = wg & 3;
  const int row0 = rowblk * GBM, c0 = colblk * GBN;
  const int wr = w >> 1, wc = w & 1;

  const int sR = l >> 2;
  const int sg = (l & 3) ^ (sR & 3);      // pre-swizzled source chunk
  const ushort* srcA0 = Af16 + (size_t)(row0 + w * 32 + sR) * NFEAT + sg * 8;
  const ushort* srcA1 = srcA0 + 16 * NFEAT;
  const ushort* srcB0 = Bf16 + (size_t)(c0 + w * 32 + sR) * NFEAT + sg * 8;
  const ushort* srcB1 = srcB0 + 16 * NFEAT;
  ushort* ldsA0 = As + w * 32 * GBK;
  ushort* ldsA1 = ldsA0 + 16 * GBK;
  ushort* ldsB0 = Bs + w * 32 * GBK;
  ushort* ldsB1 = ldsB0 + 16 * GBK;

  const int fr = l & 15, fq = l >> 4;
  const int ch = ((fq ^ (fr & 3)) * 8);   // swizzled chunk offset (ushorts)

  f32x4 acc[4][4];
  #pragma unroll
  for (int i = 0; i < 4; ++i)
    #pragma unroll
    for (int j = 0; j < 4; ++j) acc[i][j] = (f32x4){0.f, 0.f, 0.f, 0.f};

  for (int ks = 0; ks < NFEAT / GBK; ++ks) {
    __syncthreads();
    gload16(srcA0, ldsA0); gload16(srcA1, ldsA1);
    gload16(srcB0, ldsB0); gload16(srcB1, ldsB1);
    srcA0 += GBK; srcA1 += GBK; srcB0 += GBK; srcB1 += GBK;
    __syncthreads();
    f16x8 a[4], b[4];
    #pragma unroll
    for (int i = 0; i < 4; ++i)
      a[i] = *(const f16x8*)&As[(wr * 64 + i * 16 + fr) * GBK + ch];
    #pragma unroll
    for (int j = 0; j < 4; ++j)
      b[j] = *(const f16x8*)&Bs[(wc * 64 + j * 16 + fr) * GBK + ch];
    #pragma unroll
    for (int i = 0; i < 4; ++i)
      #pragma unroll
      for (int j = 0; j < 4; ++j)
        acc[i][j] = __builtin_amdgcn_mfma_f32_16x16x32_f16(a[i], b[j], acc[i][j], 0, 0, 0);
  }

  // ---- fused epilogue: per 64-col chunk: den, best, second-best, argmin ----
  const float vn = vnp[0];
  float c2j[4]; int clsj[4];
  #pragma unroll
  for (int j = 0; j < 4; ++j) {
    const int c = c0 + wc * 64 + j * 16 + fr;
    c2j[j] = c2[c];
    clsj[j] = ccls[c];
  }
  const int colchunk = colblk * 2 + wc;
  #pragma unroll
  for (int i = 0; i < 4; ++i) {
    const int rbase = row0 + wr * 64 + i * 16 + fq * 4;
    float r2v[4]; int tg[4];
    #pragma unroll
    for (int v = 0; v < 4; ++v) { r2v[v] = r2[rbase + v]; tg[v] = target[rbase + v]; }
    #pragma unroll
    for (int v = 0; v < 4; ++v) {
      float den = 0.f, bv = 3.4e38f, bv2 = 3.4e38f;
      int bc = 1 << 30;
      #pragma unroll
      for (int j = 0; j < 4; ++j) {
        const float cost = r2v[v] + c2j[j] - 2.0f * acc[i][j][v];
        if (clsj[j] != tg[v]) den += __expf(vn * cost);
        if (cost < bv) { bv2 = bv; bv = cost; bc = c0 + wc * 64 + j * 16 + fr; }
        else if (cost < bv2) { bv2 = cost; }
      }
      #pragma unroll
      for (int off = 1; off < 16; off <<= 1) {
        den += __shfl_xor(den, off);
        const float ov = __shfl_xor(bv, off);
        const float ov2 = __shfl_xor(bv2, off);
        const int oc = __shfl_xor(bc, off);
        const float nb2 = fminf(fminf(bv2, ov2), fmaxf(bv, ov));
        if (ov < bv || (ov == bv && oc < bc)) { bv = ov; bc = oc; }
        bv2 = nb2;
      }
      if (fr == 0) {
        const int idx = colchunk * NSAMP + rbase + v;
        den_p[idx] = den;
        minv_p[idx] = bv;
        minv2_p[idx] = bv2;
        minc_p[idx] = (float)bc;
      }
    }
  }
}

// ---------------- Kernel F2: combine partials; worklist append ----------------
__global__ __launch_bounds__(256) void k_fin2(const float* __restrict__ den_p,
                                              const float* __restrict__ minv_p,
                                              const float* __restrict__ minv2_p,
                                              const float* __restrict__ minc_p,
                                              const float* __restrict__ intra,
                                              const float* __restrict__ vnp,
                                              float* __restrict__ losses,
                                              float* __restrict__ preds,
                                              int* __restrict__ wl,
                                              int* __restrict__ wcount) {
  const int row = blockIdx.x * 256 + threadIdx.x;
  float den = 0.f, bv = 3.4e38f, bv2 = 3.4e38f, bc = 0.f;
  #pragma unroll
  for (int k = 0; k < NCHUNK; ++k) {
    den += den_p[k * NSAMP + row];
    const float v = minv_p[k * NSAMP + row];
    const float v2 = minv2_p[k * NSAMP + row];
    const float c = minc_p[k * NSAMP + row];
    const float nb2 = fminf(fminf(bv2, v2), fmaxf(bv, v));
    if (v < bv) { bv = v; bc = c; }   // ascending chunk -> first (lowest col) wins ties
    bv2 = nb2;
  }
  const float num = expf(vnp[0] * intra[row] - ALPHA_C);
  const float ratio = num / (den + EPS_C) + EPS_C;
  float loss = -logf(ratio);
  losses[row] = loss > 0.f ? loss : 0.f;
  preds[row] = bc;
  if (bv2 - bv < MARGIN_C) {
    int i = atomicAdd(wcount, 1);
    wl[i] = row;
  }
}

// ---------------- Kernel G: exact fp32 argmin fixup (worklist, coalesced) ---
// Block = one flagged row. Wave w scans clusters w, w+4, ...; lanes span
// features (coalesced float4 reads of means), 6-step shuffle reduce per
// cluster; lane 0 tracks best/argmin.
__global__ __launch_bounds__(256) void k_fix(const float* __restrict__ inp,
                                             const float* __restrict__ means,
                                             const float* __restrict__ c2,
                                             const float* __restrict__ r2,
                                             const int* __restrict__ wl,
                                             const int* __restrict__ wcount,
                                             float* __restrict__ preds) {
  __shared__ float rbuf[NFEAT];
  __shared__ float redv[4];
  __shared__ int redc[4];
  const int t = threadIdx.x;
  const int l = t & 63, w = t >> 6;
  const int cnt = *wcount;
  for (int i = blockIdx.x; i < cnt; i += gridDim.x) {
    const int row = wl[i];
    *(float4*)&rbuf[t * 4] = *(const float4*)(inp + (size_t)row * NFEAT + t * 4);
    __syncthreads();
    const float r2v = r2[row];
    float rb[16];
    #pragma unroll
    for (int q = 0; q < 4; ++q) {
      rb[q * 4 + 0] = rbuf[q * 256 + l * 4 + 0];
      rb[q * 4 + 1] = rbuf[q * 256 + l * 4 + 1];
      rb[q * 4 + 2] = rbuf[q * 256 + l * 4 + 2];
      rb[q * 4 + 3] = rbuf[q * 256 + l * 4 + 3];
    }
    float bv = 3.4e38f; int bc = 1 << 30;
    #pragma unroll 2
    for (int c = w; c < NCLUST; c += 4) {   // ascending within wave
      const float* mp = means + (size_t)c * NFEAT + l * 4;
      float dot = 0.f;
      #pragma unroll
      for (int q = 0; q < 4; ++q) {
        const float4 m4 = *(const float4*)(mp + q * 256);
        dot += m4.x * rb[q * 4 + 0] + m4.y * rb[q * 4 + 1] +
               m4.z * rb[q * 4 + 2] + m4.w * rb[q * 4 + 3];
      }
      #pragma unroll
      for (int off = 32; off; off >>= 1) dot += __shfl_down(dot, off);
      // lane 0 holds the full dot; sequential ascending scan, strict < keeps first
      const float cost = r2v + c2[c] - 2.0f * dot;
      if (cost < bv) { bv = cost; bc = c; }
    }
    if (l == 0) { redv[w] = bv; redc[w] = bc; }
    __syncthreads();
    if (t == 0) {
      float fbv = redv[0]; int fbc = redc[0];
      #pragma unroll
      for (int k = 1; k < 4; ++k) {
        if (redv[k] < fbv || (redv[k] == fbv && redc[k] < fbc)) { fbv = redv[k]; fbc = redc[k]; }
      }
      preds[row] = (float)fbc;
    }
    __syncthreads();
  }
}

// ---------------- Kernel F: total_loss + acc (deterministic) ----------------
__global__ __launch_bounds__(256) void k_final(const float* __restrict__ losses,
                                               const float* __restrict__ preds,
                                               float* __restrict__ out) {
  const int t = threadIdx.x;
  float s = 0.f, cnt = 0.f;
  for (int i = t; i < NSAMP; i += 256) {
    s += losses[i];
    int p = (int)preds[i];
    cnt += (p == (i >> 5)) ? 1.f : 0.f;
  }
  __shared__ float redS[4], redC[4];
  #pragma unroll
  for (int off = 32; off > 0; off >>= 1) {
    s += __shfl_down(s, off);
    cnt += __shfl_down(cnt, off);
  }
  if ((t & 63) == 0) { redS[t >> 6] = s; redC[t >> 6] = cnt; }
  __syncthreads();
  if (t == 0) {
    out[0] = (redS[0] + redS[1] + redS[2] + redS[3]) / (float)NSAMP;
    out[1 + 2 * NSAMP] = (redC[0] + redC[1] + redC[2] + redC[3]) / (float)NSAMP;
  }
}

extern "C" void kernel_launch(void* const* d_in, const int* in_sizes, int n_in,
                              void* d_out, int out_size, void* d_ws, size_t ws_size,
                              hipStream_t stream) {
  const float* inp = (const float*)d_in[0];
  const int* target = (const int*)d_in[1];
  float* out = (float*)d_out;

  ushort* Af16 = (ushort*)d_ws;                        // 16384*1024 f16 (32 MiB)
  ushort* Bf16 = Af16 + (size_t)NSAMP * NFEAT;         // 512*1024 f16 (1 MiB)
  float* means = (float*)(Bf16 + (size_t)NCLUST * NFEAT);  // 512*1024 f32
  float* c2 = means + (size_t)NCLUST * NFEAT;          // 512
  float* r2 = c2 + NCLUST;                             // 16384
  float* intra = r2 + NSAMP;                           // 16384
  float* vn = intra + NSAMP;                           // 1
  int* ccls = (int*)(vn + 1);                          // 512
  float* den_p = (float*)(ccls + NCLUST);              // 8*16384
  float* minv_p = den_p + NCHUNK * NSAMP;              // 8*16384
  float* minv2_p = minv_p + NCHUNK * NSAMP;            // 8*16384
  float* minc_p = minv2_p + NCHUNK * NSAMP;            // 8*16384
  int* wl = (int*)(minc_p + NCHUNK * NSAMP);           // 16384
  int* wcount = wl + NSAMP;                            // 1

  float* losses = out + 1;
  float* preds = out + 1 + NSAMP;

  hipLaunchKernelGGL(k_pre, dim3(NCLUST), dim3(256), 0, stream,
                     inp, target, means, Bf16, Af16, c2, r2, intra, ccls, wcount);
  hipLaunchKernelGGL(k_var, dim3(1), dim3(256), 0, stream, intra, vn);
  hipLaunchKernelGGL(k_gemm, dim3(512), dim3(256), 0, stream,
                     Af16, Bf16, c2, r2, vn, ccls, target,
                     den_p, minv_p, minv2_p, minc_p);
  hipLaunchKernelGGL(k_fin2, dim3(NSAMP / 256), dim3(256), 0, stream,
                     den_p, minv_p, minv2_p, minc_p, intra, vn, losses, preds,
                     wl, wcount);
  hipLaunchKernelGGL(k_fix, dim3(64), dim3(256), 0, stream,
                     inp, means, c2, r2, wl, wcount, preds);
  hipLaunchKernelGGL(k_final, dim3(1), dim3(256), 0, stream, losses, preds, out);
}

// Round 7
// 122.823 us; speedup vs baseline: 1.5053x; 1.5053x over previous
//
#include <hip/hip_runtime.h>
#include <math.h>

#define NCLUST 512
#define DPER 32
#define NFEAT 1024
#define NSAMP (NCLUST * DPER)   // 16384
#define ALPHA_C 1.0f
#define EPS_C 1e-8f
#define MARGIN_C 0.25f

#define GBM 128
#define GBN 128
#define GBK 32
#define NCHUNK 8   // 512 cols / 64-col wave chunks

typedef __attribute__((ext_vector_type(4))) float f32x4;
typedef __attribute__((ext_vector_type(8))) _Float16 f16x8;

__device__ __forceinline__ unsigned f2h(float f) {
  _Float16 h = (_Float16)f;
  return (unsigned)__builtin_bit_cast(ushort, h);
}

__device__ __forceinline__ void gload16(const ushort* g, ushort* l) {
  __builtin_amdgcn_global_load_lds(
      (const __attribute__((address_space(1))) unsigned int*)g,
      (__attribute__((address_space(3))) unsigned int*)l, 16, 0, 0);
}

// ---------------- Kernel PRE: means, c2, ccls, Bf16, Af16, r2, intra --------
__global__ __launch_bounds__(256) void k_pre(const float* __restrict__ inp,
                                             const int* __restrict__ target,
                                             float* __restrict__ means,
                                             ushort* __restrict__ Bf16,
                                             ushort* __restrict__ Af16,
                                             float* __restrict__ c2,
                                             float* __restrict__ r2,
                                             float* __restrict__ intra,
                                             int* __restrict__ ccls,
                                             int* __restrict__ wcount) {
  const int m = blockIdx.x;
  const int t = threadIdx.x;
  const int w = t >> 6, l = t & 63;
  __shared__ float redA[DPER][4];
  __shared__ float redB[DPER][4];
  __shared__ float red4[4];
  __shared__ float c2s;
  const float* base = inp + (size_t)m * DPER * NFEAT + t * 4;
  ushort* abase = Af16 + (size_t)m * DPER * NFEAT + t * 4;

  float sx = 0.f, sy = 0.f, sz = 0.f, sw = 0.f;
  #pragma unroll 4
  for (int d = 0; d < DPER; ++d) {
    float4 v = *(const float4*)(base + (size_t)d * NFEAT);
    sx += v.x; sy += v.y; sz += v.z; sw += v.w;
    uint2 hw;
    hw.x = f2h(v.x) | (f2h(v.y) << 16);
    hw.y = f2h(v.z) | (f2h(v.w) << 16);
    *(uint2*)(abase + (size_t)d * NFEAT) = hw;
    float p = v.x * v.x + v.y * v.y + v.z * v.z + v.w * v.w;
    #pragma unroll
    for (int off = 32; off; off >>= 1) p += __shfl_down(p, off);
    if (l == 0) redA[d][w] = p;
  }
  // mean of this cluster (4 cols per thread)
  const float inv = 1.0f / 32.0f;
  sx *= inv; sy *= inv; sz *= inv; sw *= inv;
  *(float4*)(means + (size_t)m * NFEAT + t * 4) = make_float4(sx, sy, sz, sw);
  uint2 bw;
  bw.x = f2h(sx) | (f2h(sy) << 16);
  bw.y = f2h(sz) | (f2h(sw) << 16);
  *(uint2*)&Bf16[(size_t)m * NFEAT + t * 4] = bw;
  float sq = sx * sx + sy * sy + sz * sz + sw * sw;
  #pragma unroll
  for (int off = 32; off; off >>= 1) sq += __shfl_down(sq, off);
  if (l == 0) red4[w] = sq;
  __syncthreads();
  float rr = 0.f;
  if (t < DPER) {
    rr = redA[t][0] + redA[t][1] + redA[t][2] + redA[t][3];
    r2[m * DPER + t] = rr;
  }
  if (t == 0) {
    float cc = red4[0] + red4[1] + red4[2] + red4[3];
    c2s = cc;
    c2[m] = cc;
    ccls[m] = target[m * DPER];
    if (m == 0) *wcount = 0;   // reset worklist counter each call
  }
  __syncthreads();
  const float c2v = c2s;
  // pass 2: intra dot (L2-hot re-read)
  #pragma unroll 4
  for (int d = 0; d < DPER; ++d) {
    float4 v = *(const float4*)(base + (size_t)d * NFEAT);
    float p = v.x * sx + v.y * sy + v.z * sz + v.w * sw;
    #pragma unroll
    for (int off = 32; off; off >>= 1) p += __shfl_down(p, off);
    if (l == 0) redB[d][w] = p;
  }
  __syncthreads();
  if (t < DPER) {
    float dot = redB[t][0] + redB[t][1] + redB[t][2] + redB[t][3];
    intra[m * DPER + t] = rr + c2v - 2.0f * dot;
  }
}

// ---------------- Kernel D: variance -> var_norm ----------------
__global__ __launch_bounds__(256) void k_var(const float* __restrict__ intra,
                                             float* __restrict__ vn) {
  const int t = threadIdx.x;
  float s = 0.f;
  for (int i = t; i < NSAMP; i += 256) s += intra[i];
  __shared__ float red[4];
  #pragma unroll
  for (int off = 32; off > 0; off >>= 1) s += __shfl_down(s, off);
  if ((t & 63) == 0) red[t >> 6] = s;
  __syncthreads();
  if (t == 0) {
    float tot = red[0] + red[1] + red[2] + red[3];
    float var = tot / (float)(NSAMP - 1);
    vn[0] = -1.0f / (2.0f * var * var);
  }
}

// ---------------- Kernel E: f16 MFMA GEMM (m97 template) + epilogue ----------
__global__ __launch_bounds__(256, 3) void k_gemm(
    const ushort* __restrict__ Af16, const ushort* __restrict__ Bf16,
    const float* __restrict__ c2, const float* __restrict__ r2,
    const float* __restrict__ vnp, const int* __restrict__ ccls,
    const int* __restrict__ target,
    float* __restrict__ den_p, float* __restrict__ minv_p,
    float* __restrict__ minv2_p, float* __restrict__ minc_p) {
  __shared__ ushort As[GBM * GBK];   // 8 KiB
  __shared__ ushort Bs[GBN * GBK];   // 8 KiB
  const int t = threadIdx.x;
  const int l = t & 63, w = t >> 6;
  const int wg = (blockIdx.x & 7) * 64 + (blockIdx.x >> 3);  // bijective (512%8==0)
  const int rowblk = wg >> 2, colblk = wg & 3;
  const int row0 = rowblk * GBM, c0 = colblk * GBN;
  const int wr = w >> 1, wc = w & 1;

  const int sR = l >> 2;
  const int sg = (l & 3) ^ (sR & 3);      // pre-swizzled source chunk
  const ushort* srcA0 = Af16 + (size_t)(row0 + w * 32 + sR) * NFEAT + sg * 8;
  const ushort* srcA1 = srcA0 + 16 * NFEAT;
  const ushort* srcB0 = Bf16 + (size_t)(c0 + w * 32 + sR) * NFEAT + sg * 8;
  const ushort* srcB1 = srcB0 + 16 * NFEAT;
  ushort* ldsA0 = As + w * 32 * GBK;
  ushort* ldsA1 = ldsA0 + 16 * GBK;
  ushort* ldsB0 = Bs + w * 32 * GBK;
  ushort* ldsB1 = ldsB0 + 16 * GBK;

  const int fr = l & 15, fq = l >> 4;
  const int ch = ((fq ^ (fr & 3)) * 8);   // swizzled chunk offset (ushorts)

  f32x4 acc[4][4];
  #pragma unroll
  for (int i = 0; i < 4; ++i)
    #pragma unroll
    for (int j = 0; j < 4; ++j) acc[i][j] = (f32x4){0.f, 0.f, 0.f, 0.f};

  for (int ks = 0; ks < NFEAT / GBK; ++ks) {
    __syncthreads();
    gload16(srcA0, ldsA0); gload16(srcA1, ldsA1);
    gload16(srcB0, ldsB0); gload16(srcB1, ldsB1);
    srcA0 += GBK; srcA1 += GBK; srcB0 += GBK; srcB1 += GBK;
    __syncthreads();
    f16x8 a[4], b[4];
    #pragma unroll
    for (int i = 0; i < 4; ++i)
      a[i] = *(const f16x8*)&As[(wr * 64 + i * 16 + fr) * GBK + ch];
    #pragma unroll
    for (int j = 0; j < 4; ++j)
      b[j] = *(const f16x8*)&Bs[(wc * 64 + j * 16 + fr) * GBK + ch];
    #pragma unroll
    for (int i = 0; i < 4; ++i)
      #pragma unroll
      for (int j = 0; j < 4; ++j)
        acc[i][j] = __builtin_amdgcn_mfma_f32_16x16x32_f16(a[i], b[j], acc[i][j], 0, 0, 0);
  }

  // ---- fused epilogue: per 64-col chunk: den, best, second-best, argmin ----
  const float vn = vnp[0];
  float c2j[4]; int clsj[4];
  #pragma unroll
  for (int j = 0; j < 4; ++j) {
    const int c = c0 + wc * 64 + j * 16 + fr;
    c2j[j] = c2[c];
    clsj[j] = ccls[c];
  }
  const int colchunk = colblk * 2 + wc;
  #pragma unroll
  for (int i = 0; i < 4; ++i) {
    const int rbase = row0 + wr * 64 + i * 16 + fq * 4;
    float r2v[4]; int tg[4];
    #pragma unroll
    for (int v = 0; v < 4; ++v) { r2v[v] = r2[rbase + v]; tg[v] = target[rbase + v]; }
    #pragma unroll
    for (int v = 0; v < 4; ++v) {
      float den = 0.f, bv = 3.4e38f, bv2 = 3.4e38f;
      int bc = 1 << 30;
      #pragma unroll
      for (int j = 0; j < 4; ++j) {
        const float cost = r2v[v] + c2j[j] - 2.0f * acc[i][j][v];
        if (clsj[j] != tg[v]) den += __expf(vn * cost);
        if (cost < bv) { bv2 = bv; bv = cost; bc = c0 + wc * 64 + j * 16 + fr; }
        else if (cost < bv2) { bv2 = cost; }
      }
      #pragma unroll
      for (int off = 1; off < 16; off <<= 1) {
        den += __shfl_xor(den, off);
        const float ov = __shfl_xor(bv, off);
        const float ov2 = __shfl_xor(bv2, off);
        const int oc = __shfl_xor(bc, off);
        const float nb2 = fminf(fminf(bv2, ov2), fmaxf(bv, ov));
        if (ov < bv || (ov == bv && oc < bc)) { bv = ov; bc = oc; }
        bv2 = nb2;
      }
      if (fr == 0) {
        const int idx = colchunk * NSAMP + rbase + v;
        den_p[idx] = den;
        minv_p[idx] = bv;
        minv2_p[idx] = bv2;
        minc_p[idx] = (float)bc;
      }
    }
  }
}

// ---------------- Kernel F2: combine partials; worklist append ----------------
__global__ __launch_bounds__(256) void k_fin2(const float* __restrict__ den_p,
                                              const float* __restrict__ minv_p,
                                              const float* __restrict__ minv2_p,
                                              const float* __restrict__ minc_p,
                                              const float* __restrict__ intra,
                                              const float* __restrict__ vnp,
                                              float* __restrict__ losses,
                                              float* __restrict__ preds,
                                              int* __restrict__ wl,
                                              int* __restrict__ wcount,
                                              unsigned long long* __restrict__ slots) {
  const int row = blockIdx.x * 256 + threadIdx.x;
  float den = 0.f, bv = 3.4e38f, bv2 = 3.4e38f, bc = 0.f;
  #pragma unroll
  for (int k = 0; k < NCHUNK; ++k) {
    den += den_p[k * NSAMP + row];
    const float v = minv_p[k * NSAMP + row];
    const float v2 = minv2_p[k * NSAMP + row];
    const float c = minc_p[k * NSAMP + row];
    const float nb2 = fminf(fminf(bv2, v2), fmaxf(bv, v));
    if (v < bv) { bv = v; bc = c; }   // ascending chunk -> first (lowest col) wins ties
    bv2 = nb2;
  }
  const float num = expf(vnp[0] * intra[row] - ALPHA_C);
  const float ratio = num / (den + EPS_C) + EPS_C;
  float loss = -logf(ratio);
  losses[row] = loss > 0.f ? loss : 0.f;
  preds[row] = bc;
  if (bv2 - bv < MARGIN_C) {
    slots[row] = 0xFFFFFFFFFFFFFFFFULL;   // init before k_fix's atomicMin
    int i = atomicAdd(wcount, 1);
    wl[i] = row;
  }
}

// ---------------- Kernel G: exact fp32 argmin fixup (parallel chunks) -------
// Block (wi, chunk): 8 clusters of flagged row wl[wi]; wave w -> 2 clusters.
// Coalesced means reads; u64 atomicMin on (cost_bits<<32 | cluster) -- costs
// are positive so float bits are order-preserving; ties -> lowest cluster.
__global__ __launch_bounds__(256) void k_fix(const float* __restrict__ inp,
                                             const float* __restrict__ means,
                                             const float* __restrict__ c2,
                                             const float* __restrict__ r2,
                                             const int* __restrict__ wl,
                                             const int* __restrict__ wcount,
                                             unsigned long long* __restrict__ slots) {
  __shared__ float rbuf[NFEAT];
  const int t = threadIdx.x;
  const int l = t & 63, w = t >> 6;
  const int cnt = *wcount;
  const int chunk = blockIdx.x & 63;
  for (int wi = blockIdx.x >> 6; wi < cnt; wi += gridDim.x >> 6) {
    const int row = wl[wi];
    __syncthreads();
    *(float4*)&rbuf[t * 4] = *(const float4*)(inp + (size_t)row * NFEAT + t * 4);
    __syncthreads();
    float rb[16];
    #pragma unroll
    for (int q = 0; q < 4; ++q) {
      const float4 v = *(const float4*)&rbuf[q * 256 + l * 4];
      rb[q * 4 + 0] = v.x; rb[q * 4 + 1] = v.y;
      rb[q * 4 + 2] = v.z; rb[q * 4 + 3] = v.w;
    }
    const float r2v = r2[row];
    #pragma unroll
    for (int cc = 0; cc < 2; ++cc) {
      const int c = chunk * 8 + w * 2 + cc;
      const float* mp = means + (size_t)c * NFEAT + l * 4;
      float dot = 0.f;
      #pragma unroll
      for (int q = 0; q < 4; ++q) {
        const float4 m4 = *(const float4*)(mp + q * 256);
        dot += m4.x * rb[q * 4 + 0] + m4.y * rb[q * 4 + 1] +
               m4.z * rb[q * 4 + 2] + m4.w * rb[q * 4 + 3];
      }
      #pragma unroll
      for (int off = 32; off; off >>= 1) dot += __shfl_down(dot, off);
      if (l == 0) {
        const float cost = r2v + c2[c] - 2.0f * dot;
        const unsigned long long enc =
            ((unsigned long long)__float_as_uint(cost) << 32) | (unsigned)c;
        atomicMin(&slots[row], enc);
      }
    }
  }
}

// ---------------- Kernel G2: write fixed preds ----------------
__global__ __launch_bounds__(256) void k_fixw(const int* __restrict__ wl,
                                              const int* __restrict__ wcount,
                                              const unsigned long long* __restrict__ slots,
                                              float* __restrict__ preds) {
  const int cnt = *wcount;
  for (int i = blockIdx.x * 256 + threadIdx.x; i < cnt; i += 256 * gridDim.x) {
    const int row = wl[i];
    preds[row] = (float)(unsigned)(slots[row] & 0xFFFFFFFFULL);
  }
}

// ---------------- Kernel F: total_loss + acc (deterministic) ----------------
__global__ __launch_bounds__(256) void k_final(const float* __restrict__ losses,
                                               const float* __restrict__ preds,
                                               float* __restrict__ out) {
  const int t = threadIdx.x;
  float s = 0.f, cnt = 0.f;
  for (int i = t; i < NSAMP; i += 256) {
    s += losses[i];
    int p = (int)preds[i];
    cnt += (p == (i >> 5)) ? 1.f : 0.f;
  }
  __shared__ float redS[4], redC[4];
  #pragma unroll
  for (int off = 32; off > 0; off >>= 1) {
    s += __shfl_down(s, off);
    cnt += __shfl_down(cnt, off);
  }
  if ((t & 63) == 0) { redS[t >> 6] = s; redC[t >> 6] = cnt; }
  __syncthreads();
  if (t == 0) {
    out[0] = (redS[0] + redS[1] + redS[2] + redS[3]) / (float)NSAMP;
    out[1 + 2 * NSAMP] = (redC[0] + redC[1] + redC[2] + redC[3]) / (float)NSAMP;
  }
}

extern "C" void kernel_launch(void* const* d_in, const int* in_sizes, int n_in,
                              void* d_out, int out_size, void* d_ws, size_t ws_size,
                              hipStream_t stream) {
  const float* inp = (const float*)d_in[0];
  const int* target = (const int*)d_in[1];
  float* out = (float*)d_out;

  ushort* Af16 = (ushort*)d_ws;                        // 16384*1024 f16 (32 MiB)
  ushort* Bf16 = Af16 + (size_t)NSAMP * NFEAT;         // 512*1024 f16 (1 MiB)
  unsigned long long* slots =
      (unsigned long long*)(Bf16 + (size_t)NCLUST * NFEAT);  // 16384 u64 (8-aligned)
  float* means = (float*)(slots + NSAMP);              // 512*1024 f32
  float* c2 = means + (size_t)NCLUST * NFEAT;          // 512
  float* r2 = c2 + NCLUST;                             // 16384
  float* intra = r2 + NSAMP;                           // 16384
  float* vn = intra + NSAMP;                           // 1
  int* ccls = (int*)(vn + 1);                          // 512
  float* den_p = (float*)(ccls + NCLUST);              // 8*16384
  float* minv_p = den_p + NCHUNK * NSAMP;              // 8*16384
  float* minv2_p = minv_p + NCHUNK * NSAMP;            // 8*16384
  float* minc_p = minv2_p + NCHUNK * NSAMP;            // 8*16384
  int* wl = (int*)(minc_p + NCHUNK * NSAMP);           // 16384
  int* wcount = wl + NSAMP;                            // 1

  float* losses = out + 1;
  float* preds = out + 1 + NSAMP;

  hipLaunchKernelGGL(k_pre, dim3(NCLUST), dim3(256), 0, stream,
                     inp, target, means, Bf16, Af16, c2, r2, intra, ccls, wcount);
  hipLaunchKernelGGL(k_var, dim3(1), dim3(256), 0, stream, intra, vn);
  hipLaunchKernelGGL(k_gemm, dim3(512), dim3(256), 0, stream,
                     Af16, Bf16, c2, r2, vn, ccls, target,
                     den_p, minv_p, minv2_p, minc_p);
  hipLaunchKernelGGL(k_fin2, dim3(NSAMP / 256), dim3(256), 0, stream,
                     den_p, minv_p, minv2_p, minc_p, intra, vn, losses, preds,
                     wl, wcount, slots);
  hipLaunchKernelGGL(k_fix, dim3(2048), dim3(256), 0, stream,
                     inp, means, c2, r2, wl, wcount, slots);
  hipLaunchKernelGGL(k_fixw, dim3(4), dim3(256), 0, stream,
                     wl, wcount, slots, preds);
  hipLaunchKernelGGL(k_final, dim3(1), dim3(256), 0, stream, losses, preds, out);
}

// Round 8
// 100.678 us; speedup vs baseline: 1.8364x; 1.2200x over previous
//
#include <hip/hip_runtime.h>
#include <math.h>

#define NCLUST 512
#define DPER 32
#define NFEAT 1024
#define NSAMP (NCLUST * DPER)   // 16384
#define ALPHA_C 1.0f
#define EPS_C 1e-8f
#define MARGIN_C 0.25f

#define GBM 128
#define GBN 128
#define GBK 32
#define NCHUNK 8   // 512 cols / 64-col wave chunks

typedef __attribute__((ext_vector_type(4))) float f32x4;
typedef __attribute__((ext_vector_type(8))) _Float16 f16x8;

__device__ __forceinline__ unsigned f2h(float f) {
  _Float16 h = (_Float16)f;
  return (unsigned)__builtin_bit_cast(ushort, h);
}

__device__ __forceinline__ void gload16(const ushort* g, ushort* l) {
  __builtin_amdgcn_global_load_lds(
      (const __attribute__((address_space(1))) unsigned int*)g,
      (__attribute__((address_space(3))) unsigned int*)l, 16, 0, 0);
}

// ---------------- Kernel PRE ----------------
// Block = cluster. Wave w owns rows 8w..8w+7; lane l spans cols {q*256+l*4}.
// Phase 1: stream rows (HBM): Af16 write, lane-local mean partials, per-row r2
// (6-shuffle, 8 independent chains/wave). Combine means via LDS once.
// Phase 2: L2-hot re-read for intra dot vs LDS-cached mean.
__global__ __launch_bounds__(256) void k_pre(const float* __restrict__ inp,
                                             const int* __restrict__ target,
                                             float* __restrict__ means,
                                             ushort* __restrict__ Bf16,
                                             ushort* __restrict__ Af16,
                                             float* __restrict__ c2,
                                             float* __restrict__ r2g,
                                             float* __restrict__ intra,
                                             float* __restrict__ percl,
                                             int* __restrict__ ccls,
                                             int* __restrict__ wcount) {
  const int m = blockIdx.x;
  const int t = threadIdx.x;
  const int w = t >> 6, l = t & 63;
  __shared__ float ldsm[4][NFEAT];   // per-wave mean partials (16 KiB)
  __shared__ float meanf[NFEAT];     // final mean (4 KiB)
  __shared__ float red4[4];
  __shared__ float redi[4];
  __shared__ float c2sh;

  const float* rowbase = inp + (size_t)m * DPER * NFEAT;
  ushort* arowbase = Af16 + (size_t)m * DPER * NFEAT;

  float4 macc0 = {0,0,0,0}, macc1 = {0,0,0,0}, macc2 = {0,0,0,0}, macc3 = {0,0,0,0};
  float r2keep[8];

  // ---- phase 1 ----
  #pragma unroll 2
  for (int rr = 0; rr < 8; ++rr) {
    const int d = w * 8 + rr;
    const float* rp = rowbase + (size_t)d * NFEAT + l * 4;
    const float4 v0 = *(const float4*)(rp);
    const float4 v1 = *(const float4*)(rp + 256);
    const float4 v2 = *(const float4*)(rp + 512);
    const float4 v3 = *(const float4*)(rp + 768);
    ushort* ap = arowbase + (size_t)d * NFEAT + l * 4;
    uint2 h;
    h.x = f2h(v0.x) | (f2h(v0.y) << 16); h.y = f2h(v0.z) | (f2h(v0.w) << 16);
    *(uint2*)(ap) = h;
    h.x = f2h(v1.x) | (f2h(v1.y) << 16); h.y = f2h(v1.z) | (f2h(v1.w) << 16);
    *(uint2*)(ap + 256) = h;
    h.x = f2h(v2.x) | (f2h(v2.y) << 16); h.y = f2h(v2.z) | (f2h(v2.w) << 16);
    *(uint2*)(ap + 512) = h;
    h.x = f2h(v3.x) | (f2h(v3.y) << 16); h.y = f2h(v3.z) | (f2h(v3.w) << 16);
    *(uint2*)(ap + 768) = h;
    macc0.x += v0.x; macc0.y += v0.y; macc0.z += v0.z; macc0.w += v0.w;
    macc1.x += v1.x; macc1.y += v1.y; macc1.z += v1.z; macc1.w += v1.w;
    macc2.x += v2.x; macc2.y += v2.y; macc2.z += v2.z; macc2.w += v2.w;
    macc3.x += v3.x; macc3.y += v3.y; macc3.z += v3.z; macc3.w += v3.w;
    float p = v0.x*v0.x + v0.y*v0.y + v0.z*v0.z + v0.w*v0.w
            + v1.x*v1.x + v1.y*v1.y + v1.z*v1.z + v1.w*v1.w
            + v2.x*v2.x + v2.y*v2.y + v2.z*v2.z + v2.w*v2.w
            + v3.x*v3.x + v3.y*v3.y + v3.z*v3.z + v3.w*v3.w;
    #pragma unroll
    for (int off = 32; off; off >>= 1) p += __shfl_down(p, off);
    r2keep[rr] = p;   // full sum valid on lane 0 only
  }
  if (l == 0) {
    #pragma unroll
    for (int rr = 0; rr < 8; ++rr) r2g[m * DPER + w * 8 + rr] = r2keep[rr];
  }
  *(float4*)&ldsm[w][0 * 256 + l * 4] = macc0;
  *(float4*)&ldsm[w][1 * 256 + l * 4] = macc1;
  *(float4*)&ldsm[w][2 * 256 + l * 4] = macc2;
  *(float4*)&ldsm[w][3 * 256 + l * 4] = macc3;
  __syncthreads();
  // ---- combine means: thread t owns cols t*4..t*4+3 ----
  float4 s0 = *(const float4*)&ldsm[0][t * 4];
  float4 s1 = *(const float4*)&ldsm[1][t * 4];
  float4 s2 = *(const float4*)&ldsm[2][t * 4];
  float4 s3 = *(const float4*)&ldsm[3][t * 4];
  const float inv = 1.0f / 32.0f;
  float4 mn;
  mn.x = (s0.x + s1.x + s2.x + s3.x) * inv;
  mn.y = (s0.y + s1.y + s2.y + s3.y) * inv;
  mn.z = (s0.z + s1.z + s2.z + s3.z) * inv;
  mn.w = (s0.w + s1.w + s2.w + s3.w) * inv;
  *(float4*)(means + (size_t)m * NFEAT + t * 4) = mn;
  uint2 bw;
  bw.x = f2h(mn.x) | (f2h(mn.y) << 16);
  bw.y = f2h(mn.z) | (f2h(mn.w) << 16);
  *(uint2*)&Bf16[(size_t)m * NFEAT + t * 4] = bw;
  *(float4*)&meanf[t * 4] = mn;
  float sq = mn.x * mn.x + mn.y * mn.y + mn.z * mn.z + mn.w * mn.w;
  #pragma unroll
  for (int off = 32; off; off >>= 1) sq += __shfl_down(sq, off);
  if (l == 0) red4[w] = sq;
  __syncthreads();
  if (t == 0) {
    const float cc = red4[0] + red4[1] + red4[2] + red4[3];
    c2sh = cc;
    c2[m] = cc;
    ccls[m] = target[m * DPER];
    if (m == 0) *wcount = 0;   // reset worklist counter each call
  }
  __syncthreads();
  const float c2v = c2sh;
  // ---- phase 2: intra (L2-hot re-read) ----
  float sintra = 0.f;
  #pragma unroll 2
  for (int rr = 0; rr < 8; ++rr) {
    const int d = w * 8 + rr;
    const float* rp = rowbase + (size_t)d * NFEAT + l * 4;
    const float4 v0 = *(const float4*)(rp);
    const float4 v1 = *(const float4*)(rp + 256);
    const float4 v2 = *(const float4*)(rp + 512);
    const float4 v3 = *(const float4*)(rp + 768);
    const float4 m0 = *(const float4*)&meanf[0 * 256 + l * 4];
    const float4 m1 = *(const float4*)&meanf[1 * 256 + l * 4];
    const float4 m2 = *(const float4*)&meanf[2 * 256 + l * 4];
    const float4 m3 = *(const float4*)&meanf[3 * 256 + l * 4];
    float p = v0.x*m0.x + v0.y*m0.y + v0.z*m0.z + v0.w*m0.w
            + v1.x*m1.x + v1.y*m1.y + v1.z*m1.z + v1.w*m1.w
            + v2.x*m2.x + v2.y*m2.y + v2.z*m2.z + v2.w*m2.w
            + v3.x*m3.x + v3.y*m3.y + v3.z*m3.z + v3.w*m3.w;
    #pragma unroll
    for (int off = 32; off; off >>= 1) p += __shfl_down(p, off);
    if (l == 0) {
      const float iv = r2keep[rr] + c2v - 2.0f * p;
      intra[m * DPER + d] = iv;
      sintra += iv;
    }
  }
  if (l == 0) redi[w] = sintra;
  __syncthreads();
  if (t == 0) percl[m] = redi[0] + redi[1] + redi[2] + redi[3];
}

// ---------------- Kernel D: variance -> var_norm (from percl) ----------------
__global__ __launch_bounds__(256) void k_var(const float* __restrict__ percl,
                                             float* __restrict__ vn) {
  const int t = threadIdx.x;
  float s = percl[t] + percl[t + 256];
  __shared__ float red[4];
  #pragma unroll
  for (int off = 32; off > 0; off >>= 1) s += __shfl_down(s, off);
  if ((t & 63) == 0) red[t >> 6] = s;
  __syncthreads();
  if (t == 0) {
    float tot = red[0] + red[1] + red[2] + red[3];
    float var = tot / (float)(NSAMP - 1);
    vn[0] = -1.0f / (2.0f * var * var);
  }
}

// ---------------- Kernel E: f16 MFMA GEMM (m97 template) + epilogue ----------
__global__ __launch_bounds__(256, 3) void k_gemm(
    const ushort* __restrict__ Af16, const ushort* __restrict__ Bf16,
    const float* __restrict__ c2, const float* __restrict__ r2,
    const float* __restrict__ vnp, const int* __restrict__ ccls,
    const int* __restrict__ target,
    float* __restrict__ den_p, float* __restrict__ minv_p,
    float* __restrict__ minv2_p, float* __restrict__ minc_p) {
  __shared__ ushort As[GBM * GBK];   // 8 KiB
  __shared__ ushort Bs[GBN * GBK];   // 8 KiB
  const int t = threadIdx.x;
  const int l = t & 63, w = t >> 6;
  const int wg = (blockIdx.x & 7) * 64 + (blockIdx.x >> 3);  // bijective (512%8==0)
  const int rowblk = wg >> 2, colblk = wg & 3;
  const int row0 = rowblk * GBM, c0 = colblk * GBN;
  const int wr = w >> 1, wc = w & 1;

  const int sR = l >> 2;
  const int sg = (l & 3) ^ (sR & 3);      // pre-swizzled source chunk
  const ushort* srcA0 = Af16 + (size_t)(row0 + w * 32 + sR) * NFEAT + sg * 8;
  const ushort* srcA1 = srcA0 + 16 * NFEAT;
  const ushort* srcB0 = Bf16 + (size_t)(c0 + w * 32 + sR) * NFEAT + sg * 8;
  const ushort* srcB1 = srcB0 + 16 * NFEAT;
  ushort* ldsA0 = As + w * 32 * GBK;
  ushort* ldsA1 = ldsA0 + 16 * GBK;
  ushort* ldsB0 = Bs + w * 32 * GBK;
  ushort* ldsB1 = ldsB0 + 16 * GBK;

  const int fr = l & 15, fq = l >> 4;
  const int ch = ((fq ^ (fr & 3)) * 8);   // swizzled chunk offset (ushorts)

  f32x4 acc[4][4];
  #pragma unroll
  for (int i = 0; i < 4; ++i)
    #pragma unroll
    for (int j = 0; j < 4; ++j) acc[i][j] = (f32x4){0.f, 0.f, 0.f, 0.f};

  for (int ks = 0; ks < NFEAT / GBK; ++ks) {
    __syncthreads();
    gload16(srcA0, ldsA0); gload16(srcA1, ldsA1);
    gload16(srcB0, ldsB0); gload16(srcB1, ldsB1);
    srcA0 += GBK; srcA1 += GBK; srcB0 += GBK; srcB1 += GBK;
    __syncthreads();
    f16x8 a[4], b[4];
    #pragma unroll
    for (int i = 0; i < 4; ++i)
      a[i] = *(const f16x8*)&As[(wr * 64 + i * 16 + fr) * GBK + ch];
    #pragma unroll
    for (int j = 0; j < 4; ++j)
      b[j] = *(const f16x8*)&Bs[(wc * 64 + j * 16 + fr) * GBK + ch];
    #pragma unroll
    for (int i = 0; i < 4; ++i)
      #pragma unroll
      for (int j = 0; j < 4; ++j)
        acc[i][j] = __builtin_amdgcn_mfma_f32_16x16x32_f16(a[i], b[j], acc[i][j], 0, 0, 0);
  }

  // ---- fused epilogue ----
  const float vn = vnp[0];
  float c2j[4]; int clsj[4];
  #pragma unroll
  for (int j = 0; j < 4; ++j) {
    const int c = c0 + wc * 64 + j * 16 + fr;
    c2j[j] = c2[c];
    clsj[j] = ccls[c];
  }
  const int colchunk = colblk * 2 + wc;
  #pragma unroll
  for (int i = 0; i < 4; ++i) {
    const int rbase = row0 + wr * 64 + i * 16 + fq * 4;
    float r2v[4]; int tg[4];
    #pragma unroll
    for (int v = 0; v < 4; ++v) { r2v[v] = r2[rbase + v]; tg[v] = target[rbase + v]; }
    #pragma unroll
    for (int v = 0; v < 4; ++v) {
      float den = 0.f, bv = 3.4e38f, bv2 = 3.4e38f;
      int bc = 1 << 30;
      #pragma unroll
      for (int j = 0; j < 4; ++j) {
        const float cost = r2v[v] + c2j[j] - 2.0f * acc[i][j][v];
        if (clsj[j] != tg[v]) den += __expf(vn * cost);
        if (cost < bv) { bv2 = bv; bv = cost; bc = c0 + wc * 64 + j * 16 + fr; }
        else if (cost < bv2) { bv2 = cost; }
      }
      #pragma unroll
      for (int off = 1; off < 16; off <<= 1) {
        den += __shfl_xor(den, off);
        const float ov = __shfl_xor(bv, off);
        const float ov2 = __shfl_xor(bv2, off);
        const int oc = __shfl_xor(bc, off);
        const float nb2 = fminf(fminf(bv2, ov2), fmaxf(bv, ov));
        if (ov < bv || (ov == bv && oc < bc)) { bv = ov; bc = oc; }
        bv2 = nb2;
      }
      if (fr == 0) {
        const int idx = colchunk * NSAMP + rbase + v;
        den_p[idx] = den;
        minv_p[idx] = bv;
        minv2_p[idx] = bv2;
        minc_p[idx] = (float)bc;
      }
    }
  }
}

// ---------------- Kernel F2: combine partials -> losses, slots, worklist ----
__global__ __launch_bounds__(256) void k_fin2(const float* __restrict__ den_p,
                                              const float* __restrict__ minv_p,
                                              const float* __restrict__ minv2_p,
                                              const float* __restrict__ minc_p,
                                              const float* __restrict__ intra,
                                              const float* __restrict__ vnp,
                                              float* __restrict__ losses,
                                              int* __restrict__ wl,
                                              int* __restrict__ wcount,
                                              unsigned long long* __restrict__ slots) {
  const int row = blockIdx.x * 256 + threadIdx.x;
  float den = 0.f, bv = 3.4e38f, bv2 = 3.4e38f, bc = 0.f;
  #pragma unroll
  for (int k = 0; k < NCHUNK; ++k) {
    den += den_p[k * NSAMP + row];
    const float v = minv_p[k * NSAMP + row];
    const float v2 = minv2_p[k * NSAMP + row];
    const float c = minc_p[k * NSAMP + row];
    const float nb2 = fminf(fminf(bv2, v2), fmaxf(bv, v));
    if (v < bv) { bv = v; bc = c; }   // ascending chunk -> first (lowest col) wins ties
    bv2 = nb2;
  }
  const float num = expf(vnp[0] * intra[row] - ALPHA_C);
  const float ratio = num / (den + EPS_C) + EPS_C;
  float loss = -logf(ratio);
  losses[row] = loss > 0.f ? loss : 0.f;
  if (bv2 - bv < MARGIN_C) {
    slots[row] = 0xFFFFFFFFFFFFFFFFULL;   // k_fix atomicMin target
    int i = atomicAdd(wcount, 1);
    wl[i] = row;
  } else {
    slots[row] = ((unsigned long long)__float_as_uint(bv) << 32) | (unsigned)(int)bc;
  }
}

// ---------------- Kernel G: exact fp32 argmin fixup (parallel chunks) -------
__global__ __launch_bounds__(256) void k_fix(const float* __restrict__ inp,
                                             const float* __restrict__ means,
                                             const float* __restrict__ c2,
                                             const float* __restrict__ r2,
                                             const int* __restrict__ wl,
                                             const int* __restrict__ wcount,
                                             unsigned long long* __restrict__ slots) {
  __shared__ float rbuf[NFEAT];
  const int t = threadIdx.x;
  const int l = t & 63, w = t >> 6;
  const int cnt = *wcount;
  const int chunk = blockIdx.x & 63;
  for (int wi = blockIdx.x >> 6; wi < cnt; wi += gridDim.x >> 6) {
    const int row = wl[wi];
    __syncthreads();
    *(float4*)&rbuf[t * 4] = *(const float4*)(inp + (size_t)row * NFEAT + t * 4);
    __syncthreads();
    float rb[16];
    #pragma unroll
    for (int q = 0; q < 4; ++q) {
      const float4 v = *(const float4*)&rbuf[q * 256 + l * 4];
      rb[q * 4 + 0] = v.x; rb[q * 4 + 1] = v.y;
      rb[q * 4 + 2] = v.z; rb[q * 4 + 3] = v.w;
    }
    const float r2v = r2[row];
    #pragma unroll
    for (int cc = 0; cc < 2; ++cc) {
      const int c = chunk * 8 + w * 2 + cc;
      const float* mp = means + (size_t)c * NFEAT + l * 4;
      float dot = 0.f;
      #pragma unroll
      for (int q = 0; q < 4; ++q) {
        const float4 m4 = *(const float4*)(mp + q * 256);
        dot += m4.x * rb[q * 4 + 0] + m4.y * rb[q * 4 + 1] +
               m4.z * rb[q * 4 + 2] + m4.w * rb[q * 4 + 3];
      }
      #pragma unroll
      for (int off = 32; off; off >>= 1) dot += __shfl_down(dot, off);
      if (l == 0) {
        const float cost = r2v + c2[c] - 2.0f * dot;
        const unsigned long long enc =
            ((unsigned long long)__float_as_uint(cost) << 32) | (unsigned)c;
        atomicMin(&slots[row], enc);
      }
    }
  }
}

// ---------------- Kernel F: preds from slots + total_loss + acc -------------
__global__ __launch_bounds__(256) void k_final(const float* __restrict__ losses,
                                               const unsigned long long* __restrict__ slots,
                                               float* __restrict__ preds,
                                               float* __restrict__ out) {
  const int t = threadIdx.x;
  float s = 0.f, cnt = 0.f;
  for (int i = t; i < NSAMP; i += 256) {
    s += losses[i];
    const int p = (int)(unsigned)(slots[i] & 0xFFFFFFFFULL);
    preds[i] = (float)p;
    cnt += (p == (i >> 5)) ? 1.f : 0.f;
  }
  __shared__ float redS[4], redC[4];
  #pragma unroll
  for (int off = 32; off > 0; off >>= 1) {
    s += __shfl_down(s, off);
    cnt += __shfl_down(cnt, off);
  }
  if ((t & 63) == 0) { redS[t >> 6] = s; redC[t >> 6] = cnt; }
  __syncthreads();
  if (t == 0) {
    out[0] = (redS[0] + redS[1] + redS[2] + redS[3]) / (float)NSAMP;
    out[1 + 2 * NSAMP] = (redC[0] + redC[1] + redC[2] + redC[3]) / (float)NSAMP;
  }
}

extern "C" void kernel_launch(void* const* d_in, const int* in_sizes, int n_in,
                              void* d_out, int out_size, void* d_ws, size_t ws_size,
                              hipStream_t stream) {
  const float* inp = (const float*)d_in[0];
  const int* target = (const int*)d_in[1];
  float* out = (float*)d_out;

  ushort* Af16 = (ushort*)d_ws;                        // 16384*1024 f16 (32 MiB)
  ushort* Bf16 = Af16 + (size_t)NSAMP * NFEAT;         // 512*1024 f16 (1 MiB)
  unsigned long long* slots =
      (unsigned long long*)(Bf16 + (size_t)NCLUST * NFEAT);  // 16384 u64
  float* means = (float*)(slots + NSAMP);              // 512*1024 f32
  float* c2 = means + (size_t)NCLUST * NFEAT;          // 512
  float* r2 = c2 + NCLUST;                             // 16384
  float* intra = r2 + NSAMP;                           // 16384
  float* vn = intra + NSAMP;                           // 1
  float* percl = vn + 1;                               // 512
  int* ccls = (int*)(percl + NCLUST);                  // 512
  float* den_p = (float*)(ccls + NCLUST);              // 8*16384
  float* minv_p = den_p + NCHUNK * NSAMP;              // 8*16384
  float* minv2_p = minv_p + NCHUNK * NSAMP;            // 8*16384
  float* minc_p = minv2_p + NCHUNK * NSAMP;            // 8*16384
  int* wl = (int*)(minc_p + NCHUNK * NSAMP);           // 16384
  int* wcount = wl + NSAMP;                            // 1

  float* losses = out + 1;
  float* preds = out + 1 + NSAMP;

  hipLaunchKernelGGL(k_pre, dim3(NCLUST), dim3(256), 0, stream,
                     inp, target, means, Bf16, Af16, c2, r2, intra, percl, ccls, wcount);
  hipLaunchKernelGGL(k_var, dim3(1), dim3(256), 0, stream, percl, vn);
  hipLaunchKernelGGL(k_gemm, dim3(512), dim3(256), 0, stream,
                     Af16, Bf16, c2, r2, vn, ccls, target,
                     den_p, minv_p, minv2_p, minc_p);
  hipLaunchKernelGGL(k_fin2, dim3(NSAMP / 256), dim3(256), 0, stream,
                     den_p, minv_p, minv2_p, minc_p, intra, vn, losses,
                     wl, wcount, slots);
  hipLaunchKernelGGL(k_fix, dim3(2048), dim3(256), 0, stream,
                     inp, means, c2, r2, wl, wcount, slots);
  hipLaunchKernelGGL(k_final, dim3(1), dim3(256), 0, stream,
                     losses, slots, preds, out);
}

// Round 9
// 98.091 us; speedup vs baseline: 1.8848x; 1.0264x over previous
//
#include <hip/hip_runtime.h>
#include <math.h>

#define NCLUST 512
#define DPER 32
#define NFEAT 1024
#define NSAMP (NCLUST * DPER)   // 16384
#define ALPHA_C 1.0f
#define EPS_C 1e-8f
#define MARGIN_C 0.25f

#define GBM 128
#define GBN 128
#define GBK 32
#define NCHUNK 8   // 512 cols / 64-col wave chunks

typedef __attribute__((ext_vector_type(4))) float f32x4;
typedef __attribute__((ext_vector_type(8))) _Float16 f16x8;

__device__ __forceinline__ unsigned f2h(float f) {
  _Float16 h = (_Float16)f;
  return (unsigned)__builtin_bit_cast(ushort, h);
}

__device__ __forceinline__ void gload16(const ushort* g, ushort* l) {
  __builtin_amdgcn_global_load_lds(
      (const __attribute__((address_space(1))) unsigned int*)g,
      (__attribute__((address_space(3))) unsigned int*)l, 16, 0, 0);
}

// ---------------- Kernel PRE (unchanged from round 8) ----------------
__global__ __launch_bounds__(256) void k_pre(const float* __restrict__ inp,
                                             const int* __restrict__ target,
                                             float* __restrict__ means,
                                             ushort* __restrict__ Bf16,
                                             ushort* __restrict__ Af16,
                                             float* __restrict__ c2,
                                             float* __restrict__ r2g,
                                             float* __restrict__ intra,
                                             float* __restrict__ percl,
                                             int* __restrict__ ccls,
                                             int* __restrict__ wcount) {
  const int m = blockIdx.x;
  const int t = threadIdx.x;
  const int w = t >> 6, l = t & 63;
  __shared__ float ldsm[4][NFEAT];
  __shared__ float meanf[NFEAT];
  __shared__ float red4[4];
  __shared__ float redi[4];
  __shared__ float c2sh;

  const float* rowbase = inp + (size_t)m * DPER * NFEAT;
  ushort* arowbase = Af16 + (size_t)m * DPER * NFEAT;

  float4 macc0 = {0,0,0,0}, macc1 = {0,0,0,0}, macc2 = {0,0,0,0}, macc3 = {0,0,0,0};
  float r2keep[8];

  #pragma unroll 2
  for (int rr = 0; rr < 8; ++rr) {
    const int d = w * 8 + rr;
    const float* rp = rowbase + (size_t)d * NFEAT + l * 4;
    const float4 v0 = *(const float4*)(rp);
    const float4 v1 = *(const float4*)(rp + 256);
    const float4 v2 = *(const float4*)(rp + 512);
    const float4 v3 = *(const float4*)(rp + 768);
    ushort* ap = arowbase + (size_t)d * NFEAT + l * 4;
    uint2 h;
    h.x = f2h(v0.x) | (f2h(v0.y) << 16); h.y = f2h(v0.z) | (f2h(v0.w) << 16);
    *(uint2*)(ap) = h;
    h.x = f2h(v1.x) | (f2h(v1.y) << 16); h.y = f2h(v1.z) | (f2h(v1.w) << 16);
    *(uint2*)(ap + 256) = h;
    h.x = f2h(v2.x) | (f2h(v2.y) << 16); h.y = f2h(v2.z) | (f2h(v2.w) << 16);
    *(uint2*)(ap + 512) = h;
    h.x = f2h(v3.x) | (f2h(v3.y) << 16); h.y = f2h(v3.z) | (f2h(v3.w) << 16);
    *(uint2*)(ap + 768) = h;
    macc0.x += v0.x; macc0.y += v0.y; macc0.z += v0.z; macc0.w += v0.w;
    macc1.x += v1.x; macc1.y += v1.y; macc1.z += v1.z; macc1.w += v1.w;
    macc2.x += v2.x; macc2.y += v2.y; macc2.z += v2.z; macc2.w += v2.w;
    macc3.x += v3.x; macc3.y += v3.y; macc3.z += v3.z; macc3.w += v3.w;
    float p = v0.x*v0.x + v0.y*v0.y + v0.z*v0.z + v0.w*v0.w
            + v1.x*v1.x + v1.y*v1.y + v1.z*v1.z + v1.w*v1.w
            + v2.x*v2.x + v2.y*v2.y + v2.z*v2.z + v2.w*v2.w
            + v3.x*v3.x + v3.y*v3.y + v3.z*v3.z + v3.w*v3.w;
    #pragma unroll
    for (int off = 32; off; off >>= 1) p += __shfl_down(p, off);
    r2keep[rr] = p;
  }
  if (l == 0) {
    #pragma unroll
    for (int rr = 0; rr < 8; ++rr) r2g[m * DPER + w * 8 + rr] = r2keep[rr];
  }
  *(float4*)&ldsm[w][0 * 256 + l * 4] = macc0;
  *(float4*)&ldsm[w][1 * 256 + l * 4] = macc1;
  *(float4*)&ldsm[w][2 * 256 + l * 4] = macc2;
  *(float4*)&ldsm[w][3 * 256 + l * 4] = macc3;
  __syncthreads();
  float4 s0 = *(const float4*)&ldsm[0][t * 4];
  float4 s1 = *(const float4*)&ldsm[1][t * 4];
  float4 s2 = *(const float4*)&ldsm[2][t * 4];
  float4 s3 = *(const float4*)&ldsm[3][t * 4];
  const float inv = 1.0f / 32.0f;
  float4 mn;
  mn.x = (s0.x + s1.x + s2.x + s3.x) * inv;
  mn.y = (s0.y + s1.y + s2.y + s3.y) * inv;
  mn.z = (s0.z + s1.z + s2.z + s3.z) * inv;
  mn.w = (s0.w + s1.w + s2.w + s3.w) * inv;
  *(float4*)(means + (size_t)m * NFEAT + t * 4) = mn;
  uint2 bw;
  bw.x = f2h(mn.x) | (f2h(mn.y) << 16);
  bw.y = f2h(mn.z) | (f2h(mn.w) << 16);
  *(uint2*)&Bf16[(size_t)m * NFEAT + t * 4] = bw;
  *(float4*)&meanf[t * 4] = mn;
  float sq = mn.x * mn.x + mn.y * mn.y + mn.z * mn.z + mn.w * mn.w;
  #pragma unroll
  for (int off = 32; off; off >>= 1) sq += __shfl_down(sq, off);
  if (l == 0) red4[w] = sq;
  __syncthreads();
  if (t == 0) {
    const float cc = red4[0] + red4[1] + red4[2] + red4[3];
    c2sh = cc;
    c2[m] = cc;
    ccls[m] = target[m * DPER];
    if (m == 0) *wcount = 0;
  }
  __syncthreads();
  const float c2v = c2sh;
  float sintra = 0.f;
  #pragma unroll 2
  for (int rr = 0; rr < 8; ++rr) {
    const int d = w * 8 + rr;
    const float* rp = rowbase + (size_t)d * NFEAT + l * 4;
    const float4 v0 = *(const float4*)(rp);
    const float4 v1 = *(const float4*)(rp + 256);
    const float4 v2 = *(const float4*)(rp + 512);
    const float4 v3 = *(const float4*)(rp + 768);
    const float4 m0 = *(const float4*)&meanf[0 * 256 + l * 4];
    const float4 m1 = *(const float4*)&meanf[1 * 256 + l * 4];
    const float4 m2 = *(const float4*)&meanf[2 * 256 + l * 4];
    const float4 m3 = *(const float4*)&meanf[3 * 256 + l * 4];
    float p = v0.x*m0.x + v0.y*m0.y + v0.z*m0.z + v0.w*m0.w
            + v1.x*m1.x + v1.y*m1.y + v1.z*m1.z + v1.w*m1.w
            + v2.x*m2.x + v2.y*m2.y + v2.z*m2.z + v2.w*m2.w
            + v3.x*m3.x + v3.y*m3.y + v3.z*m3.z + v3.w*m3.w;
    #pragma unroll
    for (int off = 32; off; off >>= 1) p += __shfl_down(p, off);
    if (l == 0) {
      const float iv = r2keep[rr] + c2v - 2.0f * p;
      intra[m * DPER + d] = iv;
      sintra += iv;
    }
  }
  if (l == 0) redi[w] = sintra;
  __syncthreads();
  if (t == 0) percl[m] = redi[0] + redi[1] + redi[2] + redi[3];
}

// ---------------- Kernel E: f16 MFMA GEMM, double-buffered counted-vmcnt ----
__global__ __launch_bounds__(256, 2) void k_gemm(
    const ushort* __restrict__ Af16, const ushort* __restrict__ Bf16,
    const float* __restrict__ c2, const float* __restrict__ r2,
    const float* __restrict__ percl, const int* __restrict__ ccls,
    const int* __restrict__ target,
    float* __restrict__ den_p, float* __restrict__ minv_p,
    float* __restrict__ minv2_p, float* __restrict__ minc_p) {
  __shared__ ushort As[2][GBM * GBK];   // 2 x 8 KiB
  __shared__ ushort Bs[2][GBN * GBK];   // 2 x 8 KiB
  __shared__ float redv[4];
  const int t = threadIdx.x;
  const int l = t & 63, w = t >> 6;
  const int wg = (blockIdx.x & 7) * 64 + (blockIdx.x >> 3);  // bijective (512%8==0)
  const int rowblk = wg >> 2, colblk = wg & 3;
  const int row0 = rowblk * GBM, c0 = colblk * GBN;
  const int wr = w >> 1, wc = w & 1;

  const int sR = l >> 2;
  const int sg = (l & 3) ^ (sR & 3);      // pre-swizzled source chunk
  const ushort* sA0 = Af16 + (size_t)(row0 + w * 32 + sR) * NFEAT + sg * 8;
  const ushort* sA1 = sA0 + 16 * NFEAT;
  const ushort* sB0 = Bf16 + (size_t)(c0 + w * 32 + sR) * NFEAT + sg * 8;
  const ushort* sB1 = sB0 + 16 * NFEAT;

  const int fr = l & 15, fq = l >> 4;
  const int ch = ((fq ^ (fr & 3)) * 8);   // swizzled chunk offset (ushorts)

  f32x4 acc[4][4];
  #pragma unroll
  for (int i = 0; i < 4; ++i)
    #pragma unroll
    for (int j = 0; j < 4; ++j) acc[i][j] = (f32x4){0.f, 0.f, 0.f, 0.f};

// wave-uniform LDS dests; HW scatters lane -> base + lane*16B
#define STAGE(bi, ks) do {                                        \
    gload16(sA0 + (ks) * GBK, &As[bi][w * 32 * GBK]);             \
    gload16(sA1 + (ks) * GBK, &As[bi][w * 32 * GBK + 16 * GBK]);  \
    gload16(sB0 + (ks) * GBK, &Bs[bi][w * 32 * GBK]);             \
    gload16(sB1 + (ks) * GBK, &Bs[bi][w * 32 * GBK + 16 * GBK]);  \
  } while (0)

#define COMPUTE(bi) do {                                                     \
    f16x8 a[4], b[4];                                                        \
    _Pragma("unroll") for (int i = 0; i < 4; ++i)                            \
      a[i] = *(const f16x8*)&As[bi][(wr * 64 + i * 16 + fr) * GBK + ch];     \
    _Pragma("unroll") for (int j = 0; j < 4; ++j)                            \
      b[j] = *(const f16x8*)&Bs[bi][(wc * 64 + j * 16 + fr) * GBK + ch];     \
    _Pragma("unroll") for (int i = 0; i < 4; ++i)                            \
      _Pragma("unroll") for (int j = 0; j < 4; ++j)                          \
        acc[i][j] = __builtin_amdgcn_mfma_f32_16x16x32_f16(a[i], b[j],       \
                                                           acc[i][j], 0,0,0);\
  } while (0)

  STAGE(0, 0);
  #pragma unroll 1
  for (int ks = 0; ks < NFEAT / GBK - 2; ks += 2) {
    STAGE(1, ks + 1);
    asm volatile("s_waitcnt vmcnt(4)" ::: "memory");  // current tile landed, prefetch in flight
    __builtin_amdgcn_s_barrier();
    COMPUTE(0);
    __builtin_amdgcn_s_barrier();                     // all waves done reading buf0
    STAGE(0, ks + 2);
    asm volatile("s_waitcnt vmcnt(4)" ::: "memory");
    __builtin_amdgcn_s_barrier();
    COMPUTE(1);
    __builtin_amdgcn_s_barrier();
  }
  // ks == 30: buf0 has tile 30 in flight
  STAGE(1, NFEAT / GBK - 1);
  asm volatile("s_waitcnt vmcnt(4)" ::: "memory");
  __builtin_amdgcn_s_barrier();
  COMPUTE(0);
  __builtin_amdgcn_s_barrier();
  asm volatile("s_waitcnt vmcnt(0)" ::: "memory");
  __builtin_amdgcn_s_barrier();
  COMPUTE(1);
#undef STAGE
#undef COMPUTE

  // ---- vn from percl (every block; deterministic) ----
  float vs = percl[t] + percl[t + 256];
  #pragma unroll
  for (int off = 32; off; off >>= 1) vs += __shfl_down(vs, off);
  if (l == 0) redv[w] = vs;
  __syncthreads();
  const float var = (redv[0] + redv[1] + redv[2] + redv[3]) / (float)(NSAMP - 1);
  const float vn = -1.0f / (2.0f * var * var);

  // ---- fused epilogue ----
  float c2j[4]; int clsj[4];
  #pragma unroll
  for (int j = 0; j < 4; ++j) {
    const int c = c0 + wc * 64 + j * 16 + fr;
    c2j[j] = c2[c];
    clsj[j] = ccls[c];
  }
  const int colchunk = colblk * 2 + wc;
  #pragma unroll
  for (int i = 0; i < 4; ++i) {
    const int rbase = row0 + wr * 64 + i * 16 + fq * 4;
    float r2v[4]; int tg[4];
    #pragma unroll
    for (int v = 0; v < 4; ++v) { r2v[v] = r2[rbase + v]; tg[v] = target[rbase + v]; }
    #pragma unroll
    for (int v = 0; v < 4; ++v) {
      float den = 0.f, bv = 3.4e38f, bv2 = 3.4e38f;
      int bc = 1 << 30;
      #pragma unroll
      for (int j = 0; j < 4; ++j) {
        const float cost = r2v[v] + c2j[j] - 2.0f * acc[i][j][v];
        if (clsj[j] != tg[v]) den += __expf(vn * cost);
        if (cost < bv) { bv2 = bv; bv = cost; bc = c0 + wc * 64 + j * 16 + fr; }
        else if (cost < bv2) { bv2 = cost; }
      }
      #pragma unroll
      for (int off = 1; off < 16; off <<= 1) {
        den += __shfl_xor(den, off);
        const float ov = __shfl_xor(bv, off);
        const float ov2 = __shfl_xor(bv2, off);
        const int oc = __shfl_xor(bc, off);
        const float nb2 = fminf(fminf(bv2, ov2), fmaxf(bv, ov));
        if (ov < bv || (ov == bv && oc < bc)) { bv = ov; bc = oc; }
        bv2 = nb2;
      }
      if (fr == 0) {
        const int idx = colchunk * NSAMP + rbase + v;
        den_p[idx] = den;
        minv_p[idx] = bv;
        minv2_p[idx] = bv2;
        minc_p[idx] = (float)bc;
      }
    }
  }
}

// ---------------- Kernel F2: combine partials (vn computed in-block) --------
__global__ __launch_bounds__(256) void k_fin2(const float* __restrict__ den_p,
                                              const float* __restrict__ minv_p,
                                              const float* __restrict__ minv2_p,
                                              const float* __restrict__ minc_p,
                                              const float* __restrict__ intra,
                                              const float* __restrict__ percl,
                                              float* __restrict__ losses,
                                              int* __restrict__ wl,
                                              int* __restrict__ wcount,
                                              unsigned long long* __restrict__ slots) {
  __shared__ float redv[4];
  const int t = threadIdx.x;
  float vs = percl[t] + percl[t + 256];
  #pragma unroll
  for (int off = 32; off; off >>= 1) vs += __shfl_down(vs, off);
  if ((t & 63) == 0) redv[t >> 6] = vs;
  __syncthreads();
  const float var = (redv[0] + redv[1] + redv[2] + redv[3]) / (float)(NSAMP - 1);
  const float vn = -1.0f / (2.0f * var * var);

  const int row = blockIdx.x * 256 + t;
  float den = 0.f, bv = 3.4e38f, bv2 = 3.4e38f, bc = 0.f;
  #pragma unroll
  for (int k = 0; k < NCHUNK; ++k) {
    den += den_p[k * NSAMP + row];
    const float v = minv_p[k * NSAMP + row];
    const float v2 = minv2_p[k * NSAMP + row];
    const float c = minc_p[k * NSAMP + row];
    const float nb2 = fminf(fminf(bv2, v2), fmaxf(bv, v));
    if (v < bv) { bv = v; bc = c; }
    bv2 = nb2;
  }
  const float num = expf(vn * intra[row] - ALPHA_C);
  const float ratio = num / (den + EPS_C) + EPS_C;
  float loss = -logf(ratio);
  losses[row] = loss > 0.f ? loss : 0.f;
  if (bv2 - bv < MARGIN_C) {
    slots[row] = 0xFFFFFFFFFFFFFFFFULL;
    int i = atomicAdd(wcount, 1);
    wl[i] = row;
  } else {
    slots[row] = ((unsigned long long)__float_as_uint(bv) << 32) | (unsigned)(int)bc;
  }
}

// ---------------- Kernel G: exact fp32 argmin fixup (parallel chunks) -------
__global__ __launch_bounds__(256) void k_fix(const float* __restrict__ inp,
                                             const float* __restrict__ means,
                                             const float* __restrict__ c2,
                                             const float* __restrict__ r2,
                                             const int* __restrict__ wl,
                                             const int* __restrict__ wcount,
                                             unsigned long long* __restrict__ slots) {
  __shared__ float rbuf[NFEAT];
  const int t = threadIdx.x;
  const int l = t & 63, w = t >> 6;
  const int cnt = *wcount;
  const int chunk = blockIdx.x & 63;
  for (int wi = blockIdx.x >> 6; wi < cnt; wi += gridDim.x >> 6) {
    const int row = wl[wi];
    __syncthreads();
    *(float4*)&rbuf[t * 4] = *(const float4*)(inp + (size_t)row * NFEAT + t * 4);
    __syncthreads();
    float rb[16];
    #pragma unroll
    for (int q = 0; q < 4; ++q) {
      const float4 v = *(const float4*)&rbuf[q * 256 + l * 4];
      rb[q * 4 + 0] = v.x; rb[q * 4 + 1] = v.y;
      rb[q * 4 + 2] = v.z; rb[q * 4 + 3] = v.w;
    }
    const float r2v = r2[row];
    #pragma unroll
    for (int cc = 0; cc < 2; ++cc) {
      const int c = chunk * 8 + w * 2 + cc;
      const float* mp = means + (size_t)c * NFEAT + l * 4;
      float dot = 0.f;
      #pragma unroll
      for (int q = 0; q < 4; ++q) {
        const float4 m4 = *(const float4*)(mp + q * 256);
        dot += m4.x * rb[q * 4 + 0] + m4.y * rb[q * 4 + 1] +
               m4.z * rb[q * 4 + 2] + m4.w * rb[q * 4 + 3];
      }
      #pragma unroll
      for (int off = 32; off; off >>= 1) dot += __shfl_down(dot, off);
      if (l == 0) {
        const float cost = r2v + c2[c] - 2.0f * dot;
        const unsigned long long enc =
            ((unsigned long long)__float_as_uint(cost) << 32) | (unsigned)c;
        atomicMin(&slots[row], enc);
      }
    }
  }
}

// ---------------- Kernel F: preds from slots + total_loss + acc -------------
__global__ __launch_bounds__(256) void k_final(const float* __restrict__ losses,
                                               const unsigned long long* __restrict__ slots,
                                               float* __restrict__ preds,
                                               float* __restrict__ out) {
  const int t = threadIdx.x;
  float s = 0.f, cnt = 0.f;
  for (int i = t; i < NSAMP; i += 256) {
    s += losses[i];
    const int p = (int)(unsigned)(slots[i] & 0xFFFFFFFFULL);
    preds[i] = (float)p;
    cnt += (p == (i >> 5)) ? 1.f : 0.f;
  }
  __shared__ float redS[4], redC[4];
  #pragma unroll
  for (int off = 32; off > 0; off >>= 1) {
    s += __shfl_down(s, off);
    cnt += __shfl_down(cnt, off);
  }
  if ((t & 63) == 0) { redS[t >> 6] = s; redC[t >> 6] = cnt; }
  __syncthreads();
  if (t == 0) {
    out[0] = (redS[0] + redS[1] + redS[2] + redS[3]) / (float)NSAMP;
    out[1 + 2 * NSAMP] = (redC[0] + redC[1] + redC[2] + redC[3]) / (float)NSAMP;
  }
}

extern "C" void kernel_launch(void* const* d_in, const int* in_sizes, int n_in,
                              void* d_out, int out_size, void* d_ws, size_t ws_size,
                              hipStream_t stream) {
  const float* inp = (const float*)d_in[0];
  const int* target = (const int*)d_in[1];
  float* out = (float*)d_out;

  ushort* Af16 = (ushort*)d_ws;                        // 16384*1024 f16 (32 MiB)
  ushort* Bf16 = Af16 + (size_t)NSAMP * NFEAT;         // 512*1024 f16 (1 MiB)
  unsigned long long* slots =
      (unsigned long long*)(Bf16 + (size_t)NCLUST * NFEAT);  // 16384 u64
  float* means = (float*)(slots + NSAMP);              // 512*1024 f32
  float* c2 = means + (size_t)NCLUST * NFEAT;          // 512
  float* r2 = c2 + NCLUST;                             // 16384
  float* intra = r2 + NSAMP;                           // 16384
  float* vn = intra + NSAMP;                           // 1 (unused, layout keep)
  float* percl = vn + 1;                               // 512
  int* ccls = (int*)(percl + NCLUST);                  // 512
  float* den_p = (float*)(ccls + NCLUST);              // 8*16384
  float* minv_p = den_p + NCHUNK * NSAMP;              // 8*16384
  float* minv2_p = minv_p + NCHUNK * NSAMP;            // 8*16384
  float* minc_p = minv2_p + NCHUNK * NSAMP;            // 8*16384
  int* wl = (int*)(minc_p + NCHUNK * NSAMP);           // 16384
  int* wcount = wl + NSAMP;                            // 1

  float* losses = out + 1;
  float* preds = out + 1 + NSAMP;

  hipLaunchKernelGGL(k_pre, dim3(NCLUST), dim3(256), 0, stream,
                     inp, target, means, Bf16, Af16, c2, r2, intra, percl, ccls, wcount);
  hipLaunchKernelGGL(k_gemm, dim3(512), dim3(256), 0, stream,
                     Af16, Bf16, c2, r2, percl, ccls, target,
                     den_p, minv_p, minv2_p, minc_p);
  hipLaunchKernelGGL(k_fin2, dim3(NSAMP / 256), dim3(256), 0, stream,
                     den_p, minv_p, minv2_p, minc_p, intra, percl, losses,
                     wl, wcount, slots);
  hipLaunchKernelGGL(k_fix, dim3(2048), dim3(256), 0, stream,
                     inp, means, c2, r2, wl, wcount, slots);
  hipLaunchKernelGGL(k_final, dim3(1), dim3(256), 0, stream,
                     losses, slots, preds, out);
}

// Round 10
// 88.666 us; speedup vs baseline: 2.0852x; 1.1063x over previous
//
#include <hip/hip_runtime.h>
#include <math.h>

#define NCLUST 512
#define DPER 32
#define NFEAT 1024
#define NSAMP (NCLUST * DPER)   // 16384
#define ALPHA_C 1.0f
#define EPS_C 1e-8f
#define MARGIN_C 0.25f

#define GBM 128
#define GBN 128
#define GBK 32
#define NCHUNK 8   // 512 cols / 64-col wave chunks

typedef __attribute__((ext_vector_type(4))) float f32x4;
typedef __attribute__((ext_vector_type(8))) _Float16 f16x8;

__device__ __forceinline__ unsigned f2h(float f) {
  _Float16 h = (_Float16)f;
  return (unsigned)__builtin_bit_cast(ushort, h);
}

__device__ __forceinline__ void gload16(const ushort* g, ushort* l) {
  __builtin_amdgcn_global_load_lds(
      (const __attribute__((address_space(1))) unsigned int*)g,
      (__attribute__((address_space(3))) unsigned int*)l, 16, 0, 0);
}

// ---------------- Kernel PRE (single pass) ----------------
// Block = cluster. Wave w owns rows 8w..8w+7; lane l spans cols {q*256+l*4}.
// Stream rows once: Af16 write, lane-local mean partials, per-row r2.
// percl via identity: sum_d |x_d - mu|^2 = sum_d |x_d|^2 - 32*|mu|^2.
// Per-row intra is produced by k_gemm (own-cluster cost), not here.
__global__ __launch_bounds__(256) void k_pre(const float* __restrict__ inp,
                                             const int* __restrict__ target,
                                             float* __restrict__ means,
                                             ushort* __restrict__ Bf16,
                                             ushort* __restrict__ Af16,
                                             float* __restrict__ c2,
                                             float* __restrict__ r2g,
                                             float* __restrict__ percl,
                                             int* __restrict__ ccls,
                                             int* __restrict__ wcount) {
  const int m = blockIdx.x;
  const int t = threadIdx.x;
  const int w = t >> 6, l = t & 63;
  __shared__ float ldsm[4][NFEAT];   // per-wave mean partials (16 KiB)
  __shared__ float red4[4];
  __shared__ float redi[4];

  const float* rowbase = inp + (size_t)m * DPER * NFEAT;
  ushort* arowbase = Af16 + (size_t)m * DPER * NFEAT;

  float4 macc0 = {0,0,0,0}, macc1 = {0,0,0,0}, macc2 = {0,0,0,0}, macc3 = {0,0,0,0};
  float r2keep[8];

  #pragma unroll 2
  for (int rr = 0; rr < 8; ++rr) {
    const int d = w * 8 + rr;
    const float* rp = rowbase + (size_t)d * NFEAT + l * 4;
    const float4 v0 = *(const float4*)(rp);
    const float4 v1 = *(const float4*)(rp + 256);
    const float4 v2 = *(const float4*)(rp + 512);
    const float4 v3 = *(const float4*)(rp + 768);
    ushort* ap = arowbase + (size_t)d * NFEAT + l * 4;
    uint2 h;
    h.x = f2h(v0.x) | (f2h(v0.y) << 16); h.y = f2h(v0.z) | (f2h(v0.w) << 16);
    *(uint2*)(ap) = h;
    h.x = f2h(v1.x) | (f2h(v1.y) << 16); h.y = f2h(v1.z) | (f2h(v1.w) << 16);
    *(uint2*)(ap + 256) = h;
    h.x = f2h(v2.x) | (f2h(v2.y) << 16); h.y = f2h(v2.z) | (f2h(v2.w) << 16);
    *(uint2*)(ap + 512) = h;
    h.x = f2h(v3.x) | (f2h(v3.y) << 16); h.y = f2h(v3.z) | (f2h(v3.w) << 16);
    *(uint2*)(ap + 768) = h;
    macc0.x += v0.x; macc0.y += v0.y; macc0.z += v0.z; macc0.w += v0.w;
    macc1.x += v1.x; macc1.y += v1.y; macc1.z += v1.z; macc1.w += v1.w;
    macc2.x += v2.x; macc2.y += v2.y; macc2.z += v2.z; macc2.w += v2.w;
    macc3.x += v3.x; macc3.y += v3.y; macc3.z += v3.z; macc3.w += v3.w;
    float p = v0.x*v0.x + v0.y*v0.y + v0.z*v0.z + v0.w*v0.w
            + v1.x*v1.x + v1.y*v1.y + v1.z*v1.z + v1.w*v1.w
            + v2.x*v2.x + v2.y*v2.y + v2.z*v2.z + v2.w*v2.w
            + v3.x*v3.x + v3.y*v3.y + v3.z*v3.z + v3.w*v3.w;
    #pragma unroll
    for (int off = 32; off; off >>= 1) p += __shfl_down(p, off);
    r2keep[rr] = p;   // full sum valid on lane 0 only
  }
  if (l == 0) {
    float r2s = 0.f;
    #pragma unroll
    for (int rr = 0; rr < 8; ++rr) {
      r2g[m * DPER + w * 8 + rr] = r2keep[rr];
      r2s += r2keep[rr];
    }
    redi[w] = r2s;
  }
  *(float4*)&ldsm[w][0 * 256 + l * 4] = macc0;
  *(float4*)&ldsm[w][1 * 256 + l * 4] = macc1;
  *(float4*)&ldsm[w][2 * 256 + l * 4] = macc2;
  *(float4*)&ldsm[w][3 * 256 + l * 4] = macc3;
  __syncthreads();
  // combine means: thread t owns cols t*4..t*4+3
  float4 s0 = *(const float4*)&ldsm[0][t * 4];
  float4 s1 = *(const float4*)&ldsm[1][t * 4];
  float4 s2 = *(const float4*)&ldsm[2][t * 4];
  float4 s3 = *(const float4*)&ldsm[3][t * 4];
  const float inv = 1.0f / 32.0f;
  float4 mn;
  mn.x = (s0.x + s1.x + s2.x + s3.x) * inv;
  mn.y = (s0.y + s1.y + s2.y + s3.y) * inv;
  mn.z = (s0.z + s1.z + s2.z + s3.z) * inv;
  mn.w = (s0.w + s1.w + s2.w + s3.w) * inv;
  *(float4*)(means + (size_t)m * NFEAT + t * 4) = mn;
  uint2 bw;
  bw.x = f2h(mn.x) | (f2h(mn.y) << 16);
  bw.y = f2h(mn.z) | (f2h(mn.w) << 16);
  *(uint2*)&Bf16[(size_t)m * NFEAT + t * 4] = bw;
  float sq = mn.x * mn.x + mn.y * mn.y + mn.z * mn.z + mn.w * mn.w;
  #pragma unroll
  for (int off = 32; off; off >>= 1) sq += __shfl_down(sq, off);
  if (l == 0) red4[w] = sq;
  __syncthreads();
  if (t == 0) {
    const float cc = red4[0] + red4[1] + red4[2] + red4[3];
    c2[m] = cc;
    ccls[m] = target[m * DPER];
    // sum_d intra = sum_d r2 - 32*c2 (exact identity)
    percl[m] = (redi[0] + redi[1] + redi[2] + redi[3]) - 32.0f * cc;
    if (m == 0) *wcount = 0;
  }
}

// ---------------- Kernel E: f16 MFMA GEMM, dbuf counted-vmcnt + intra out ---
__global__ __launch_bounds__(256, 2) void k_gemm(
    const ushort* __restrict__ Af16, const ushort* __restrict__ Bf16,
    const float* __restrict__ c2, const float* __restrict__ r2,
    const float* __restrict__ percl, const int* __restrict__ ccls,
    const int* __restrict__ target,
    float* __restrict__ den_p, float* __restrict__ minv_p,
    float* __restrict__ minv2_p, float* __restrict__ minc_p,
    float* __restrict__ intra_g) {
  __shared__ ushort As[2][GBM * GBK];   // 2 x 8 KiB
  __shared__ ushort Bs[2][GBN * GBK];   // 2 x 8 KiB
  __shared__ float redv[4];
  const int t = threadIdx.x;
  const int l = t & 63, w = t >> 6;
  const int wg = (blockIdx.x & 7) * 64 + (blockIdx.x >> 3);  // bijective (512%8==0)
  const int rowblk = wg >> 2, colblk = wg & 3;
  const int row0 = rowblk * GBM, c0 = colblk * GBN;
  const int wr = w >> 1, wc = w & 1;

  const int sR = l >> 2;
  const int sg = (l & 3) ^ (sR & 3);      // pre-swizzled source chunk
  const ushort* sA0 = Af16 + (size_t)(row0 + w * 32 + sR) * NFEAT + sg * 8;
  const ushort* sA1 = sA0 + 16 * NFEAT;
  const ushort* sB0 = Bf16 + (size_t)(c0 + w * 32 + sR) * NFEAT + sg * 8;
  const ushort* sB1 = sB0 + 16 * NFEAT;

  const int fr = l & 15, fq = l >> 4;
  const int ch = ((fq ^ (fr & 3)) * 8);   // swizzled chunk offset (ushorts)

  f32x4 acc[4][4];
  #pragma unroll
  for (int i = 0; i < 4; ++i)
    #pragma unroll
    for (int j = 0; j < 4; ++j) acc[i][j] = (f32x4){0.f, 0.f, 0.f, 0.f};

#define STAGE(bi, ks) do {                                        \
    gload16(sA0 + (ks) * GBK, &As[bi][w * 32 * GBK]);             \
    gload16(sA1 + (ks) * GBK, &As[bi][w * 32 * GBK + 16 * GBK]);  \
    gload16(sB0 + (ks) * GBK, &Bs[bi][w * 32 * GBK]);             \
    gload16(sB1 + (ks) * GBK, &Bs[bi][w * 32 * GBK + 16 * GBK]);  \
  } while (0)

#define COMPUTE(bi) do {                                                     \
    f16x8 a[4], b[4];                                                        \
    _Pragma("unroll") for (int i = 0; i < 4; ++i)                            \
      a[i] = *(const f16x8*)&As[bi][(wr * 64 + i * 16 + fr) * GBK + ch];     \
    _Pragma("unroll") for (int j = 0; j < 4; ++j)                            \
      b[j] = *(const f16x8*)&Bs[bi][(wc * 64 + j * 16 + fr) * GBK + ch];     \
    _Pragma("unroll") for (int i = 0; i < 4; ++i)                            \
      _Pragma("unroll") for (int j = 0; j < 4; ++j)                          \
        acc[i][j] = __builtin_amdgcn_mfma_f32_16x16x32_f16(a[i], b[j],       \
                                                           acc[i][j], 0,0,0);\
  } while (0)

  STAGE(0, 0);
  #pragma unroll 1
  for (int ks = 0; ks < NFEAT / GBK - 2; ks += 2) {
    STAGE(1, ks + 1);
    asm volatile("s_waitcnt vmcnt(4)" ::: "memory");
    __builtin_amdgcn_s_barrier();
    COMPUTE(0);
    __builtin_amdgcn_s_barrier();
    STAGE(0, ks + 2);
    asm volatile("s_waitcnt vmcnt(4)" ::: "memory");
    __builtin_amdgcn_s_barrier();
    COMPUTE(1);
    __builtin_amdgcn_s_barrier();
  }
  STAGE(1, NFEAT / GBK - 1);
  asm volatile("s_waitcnt vmcnt(4)" ::: "memory");
  __builtin_amdgcn_s_barrier();
  COMPUTE(0);
  __builtin_amdgcn_s_barrier();
  asm volatile("s_waitcnt vmcnt(0)" ::: "memory");
  __builtin_amdgcn_s_barrier();
  COMPUTE(1);
#undef STAGE
#undef COMPUTE

  // ---- vn from percl (every block; deterministic) ----
  float vs = percl[t] + percl[t + 256];
  #pragma unroll
  for (int off = 32; off; off >>= 1) vs += __shfl_down(vs, off);
  if (l == 0) redv[w] = vs;
  __syncthreads();
  const float var = (redv[0] + redv[1] + redv[2] + redv[3]) / (float)(NSAMP - 1);
  const float vn = -1.0f / (2.0f * var * var);

  // ---- fused epilogue ----
  float c2j[4]; int clsj[4], cjv[4];
  #pragma unroll
  for (int j = 0; j < 4; ++j) {
    const int c = c0 + wc * 64 + j * 16 + fr;
    cjv[j] = c;
    c2j[j] = c2[c];
    clsj[j] = ccls[c];
  }
  const int colchunk = colblk * 2 + wc;
  #pragma unroll
  for (int i = 0; i < 4; ++i) {
    const int rbase = row0 + wr * 64 + i * 16 + fq * 4;
    const int cm = rbase >> 5;   // own cluster (same for rows rbase..rbase+3)
    float r2v[4]; int tg[4];
    #pragma unroll
    for (int v = 0; v < 4; ++v) { r2v[v] = r2[rbase + v]; tg[v] = target[rbase + v]; }
    #pragma unroll
    for (int v = 0; v < 4; ++v) {
      float den = 0.f, bv = 3.4e38f, bv2 = 3.4e38f;
      int bc = 1 << 30;
      #pragma unroll
      for (int j = 0; j < 4; ++j) {
        const float cost = r2v[v] + c2j[j] - 2.0f * acc[i][j][v];
        if (clsj[j] != tg[v]) den += __expf(vn * cost);
        if (cjv[j] == cm) intra_g[rbase + v] = cost;   // per-row intra (one lane)
        if (cost < bv) { bv2 = bv; bv = cost; bc = cjv[j]; }
        else if (cost < bv2) { bv2 = cost; }
      }
      #pragma unroll
      for (int off = 1; off < 16; off <<= 1) {
        den += __shfl_xor(den, off);
        const float ov = __shfl_xor(bv, off);
        const float ov2 = __shfl_xor(bv2, off);
        const int oc = __shfl_xor(bc, off);
        const float nb2 = fminf(fminf(bv2, ov2), fmaxf(bv, ov));
        if (ov < bv || (ov == bv && oc < bc)) { bv = ov; bc = oc; }
        bv2 = nb2;
      }
      if (fr == 0) {
        const int idx = colchunk * NSAMP + rbase + v;
        den_p[idx] = den;
        minv_p[idx] = bv;
        minv2_p[idx] = bv2;
        minc_p[idx] = (float)bc;
      }
    }
  }
}

// ---------------- Kernel F2: combine partials (vn from percl) ----------------
__global__ __launch_bounds__(256) void k_fin2(const float* __restrict__ den_p,
                                              const float* __restrict__ minv_p,
                                              const float* __restrict__ minv2_p,
                                              const float* __restrict__ minc_p,
                                              const float* __restrict__ intra_g,
                                              const float* __restrict__ percl,
                                              float* __restrict__ losses,
                                              int* __restrict__ wl,
                                              int* __restrict__ wcount,
                                              unsigned long long* __restrict__ slots) {
  __shared__ float redv[4];
  const int t = threadIdx.x;
  float vs = percl[t] + percl[t + 256];
  #pragma unroll
  for (int off = 32; off; off >>= 1) vs += __shfl_down(vs, off);
  if ((t & 63) == 0) redv[t >> 6] = vs;
  __syncthreads();
  const float var = (redv[0] + redv[1] + redv[2] + redv[3]) / (float)(NSAMP - 1);
  const float vn = -1.0f / (2.0f * var * var);

  const int row = blockIdx.x * 256 + t;
  float den = 0.f, bv = 3.4e38f, bv2 = 3.4e38f, bc = 0.f;
  #pragma unroll
  for (int k = 0; k < NCHUNK; ++k) {
    den += den_p[k * NSAMP + row];
    const float v = minv_p[k * NSAMP + row];
    const float v2 = minv2_p[k * NSAMP + row];
    const float c = minc_p[k * NSAMP + row];
    const float nb2 = fminf(fminf(bv2, v2), fmaxf(bv, v));
    if (v < bv) { bv = v; bc = c; }
    bv2 = nb2;
  }
  const float num = expf(vn * intra_g[row] - ALPHA_C);
  const float ratio = num / (den + EPS_C) + EPS_C;
  float loss = -logf(ratio);
  losses[row] = loss > 0.f ? loss : 0.f;
  if (bv2 - bv < MARGIN_C) {
    slots[row] = 0xFFFFFFFFFFFFFFFFULL;
    int i = atomicAdd(wcount, 1);
    wl[i] = row;
  } else {
    slots[row] = ((unsigned long long)__float_as_uint(bv) << 32) | (unsigned)(int)bc;
  }
}

// ---------------- Kernel G: exact fp32 argmin fixup (parallel chunks) -------
__global__ __launch_bounds__(256) void k_fix(const float* __restrict__ inp,
                                             const float* __restrict__ means,
                                             const float* __restrict__ c2,
                                             const float* __restrict__ r2,
                                             const int* __restrict__ wl,
                                             const int* __restrict__ wcount,
                                             unsigned long long* __restrict__ slots) {
  __shared__ float rbuf[NFEAT];
  const int t = threadIdx.x;
  const int l = t & 63, w = t >> 6;
  const int cnt = *wcount;
  const int chunk = blockIdx.x & 63;
  for (int wi = blockIdx.x >> 6; wi < cnt; wi += gridDim.x >> 6) {
    const int row = wl[wi];
    __syncthreads();
    *(float4*)&rbuf[t * 4] = *(const float4*)(inp + (size_t)row * NFEAT + t * 4);
    __syncthreads();
    float rb[16];
    #pragma unroll
    for (int q = 0; q < 4; ++q) {
      const float4 v = *(const float4*)&rbuf[q * 256 + l * 4];
      rb[q * 4 + 0] = v.x; rb[q * 4 + 1] = v.y;
      rb[q * 4 + 2] = v.z; rb[q * 4 + 3] = v.w;
    }
    const float r2v = r2[row];
    #pragma unroll
    for (int cc = 0; cc < 2; ++cc) {
      const int c = chunk * 8 + w * 2 + cc;
      const float* mp = means + (size_t)c * NFEAT + l * 4;
      float dot = 0.f;
      #pragma unroll
      for (int q = 0; q < 4; ++q) {
        const float4 m4 = *(const float4*)(mp + q * 256);
        dot += m4.x * rb[q * 4 + 0] + m4.y * rb[q * 4 + 1] +
               m4.z * rb[q * 4 + 2] + m4.w * rb[q * 4 + 3];
      }
      #pragma unroll
      for (int off = 32; off; off >>= 1) dot += __shfl_down(dot, off);
      if (l == 0) {
        const float cost = r2v + c2[c] - 2.0f * dot;
        const unsigned long long enc =
            ((unsigned long long)__float_as_uint(cost) << 32) | (unsigned)c;
        atomicMin(&slots[row], enc);
      }
    }
  }
}

// ---------------- Kernel F: preds from slots + total_loss + acc -------------
__global__ __launch_bounds__(256) void k_final(const float* __restrict__ losses,
                                               const unsigned long long* __restrict__ slots,
                                               float* __restrict__ preds,
                                               float* __restrict__ out) {
  const int t = threadIdx.x;
  float s = 0.f, cnt = 0.f;
  for (int i = t; i < NSAMP; i += 256) {
    s += losses[i];
    const int p = (int)(unsigned)(slots[i] & 0xFFFFFFFFULL);
    preds[i] = (float)p;
    cnt += (p == (i >> 5)) ? 1.f : 0.f;
  }
  __shared__ float redS[4], redC[4];
  #pragma unroll
  for (int off = 32; off > 0; off >>= 1) {
    s += __shfl_down(s, off);
    cnt += __shfl_down(cnt, off);
  }
  if ((t & 63) == 0) { redS[t >> 6] = s; redC[t >> 6] = cnt; }
  __syncthreads();
  if (t == 0) {
    out[0] = (redS[0] + redS[1] + redS[2] + redS[3]) / (float)NSAMP;
    out[1 + 2 * NSAMP] = (redC[0] + redC[1] + redC[2] + redC[3]) / (float)NSAMP;
  }
}

extern "C" void kernel_launch(void* const* d_in, const int* in_sizes, int n_in,
                              void* d_out, int out_size, void* d_ws, size_t ws_size,
                              hipStream_t stream) {
  const float* inp = (const float*)d_in[0];
  const int* target = (const int*)d_in[1];
  float* out = (float*)d_out;

  ushort* Af16 = (ushort*)d_ws;                        // 16384*1024 f16 (32 MiB)
  ushort* Bf16 = Af16 + (size_t)NSAMP * NFEAT;         // 512*1024 f16 (1 MiB)
  unsigned long long* slots =
      (unsigned long long*)(Bf16 + (size_t)NCLUST * NFEAT);  // 16384 u64
  float* means = (float*)(slots + NSAMP);              // 512*1024 f32
  float* c2 = means + (size_t)NCLUST * NFEAT;          // 512
  float* r2 = c2 + NCLUST;                             // 16384
  float* intra_g = r2 + NSAMP;                         // 16384 (written by k_gemm)
  float* vn = intra_g + NSAMP;                         // 1 (unused, layout keep)
  float* percl = vn + 1;                               // 512
  int* ccls = (int*)(percl + NCLUST);                  // 512
  float* den_p = (float*)(ccls + NCLUST);              // 8*16384
  float* minv_p = den_p + NCHUNK * NSAMP;              // 8*16384
  float* minv2_p = minv_p + NCHUNK * NSAMP;            // 8*16384
  float* minc_p = minv2_p + NCHUNK * NSAMP;            // 8*16384
  int* wl = (int*)(minc_p + NCHUNK * NSAMP);           // 16384
  int* wcount = wl + NSAMP;                            // 1

  float* losses = out + 1;
  float* preds = out + 1 + NSAMP;

  hipLaunchKernelGGL(k_pre, dim3(NCLUST), dim3(256), 0, stream,
                     inp, target, means, Bf16, Af16, c2, r2, percl, ccls, wcount);
  hipLaunchKernelGGL(k_gemm, dim3(512), dim3(256), 0, stream,
                     Af16, Bf16, c2, r2, percl, ccls, target,
                     den_p, minv_p, minv2_p, minc_p, intra_g);
  hipLaunchKernelGGL(k_fin2, dim3(NSAMP / 256), dim3(256), 0, stream,
                     den_p, minv_p, minv2_p, minc_p, intra_g, percl, losses,
                     wl, wcount, slots);
  hipLaunchKernelGGL(k_fix, dim3(2048), dim3(256), 0, stream,
                     inp, means, c2, r2, wl, wcount, slots);
  hipLaunchKernelGGL(k_final, dim3(1), dim3(256), 0, stream,
                     losses, slots, preds, out);
}

// Round 11
// 84.292 us; speedup vs baseline: 2.1934x; 1.0519x over previous
//
#include <hip/hip_runtime.h>
#include <math.h>

#define NCLUST 512
#define DPER 32
#define NFEAT 1024
#define NSAMP (NCLUST * DPER)   // 16384
#define ALPHA_C 1.0f
#define EPS_C 1e-8f
#define MARGIN_C 0.25f

#define GBM 128
#define GBN 128
#define GBK 64
#define NCHUNK 8   // 512 cols / 64-col wave chunks

typedef __attribute__((ext_vector_type(4))) float f32x4;
typedef __attribute__((ext_vector_type(8))) _Float16 f16x8;

__device__ __forceinline__ unsigned f2h(float f) {
  _Float16 h = (_Float16)f;
  return (unsigned)__builtin_bit_cast(ushort, h);
}

__device__ __forceinline__ void gload16(const ushort* g, ushort* l) {
  __builtin_amdgcn_global_load_lds(
      (const __attribute__((address_space(1))) unsigned int*)g,
      (__attribute__((address_space(3))) unsigned int*)l, 16, 0, 0);
}

// ---------------- Kernel PRE (single pass, unchanged) ----------------
__global__ __launch_bounds__(256) void k_pre(const float* __restrict__ inp,
                                             const int* __restrict__ target,
                                             float* __restrict__ means,
                                             ushort* __restrict__ Bf16,
                                             ushort* __restrict__ Af16,
                                             float* __restrict__ c2,
                                             float* __restrict__ r2g,
                                             float* __restrict__ percl,
                                             int* __restrict__ ccls,
                                             int* __restrict__ wcount) {
  const int m = blockIdx.x;
  const int t = threadIdx.x;
  const int w = t >> 6, l = t & 63;
  __shared__ float ldsm[4][NFEAT];   // per-wave mean partials (16 KiB)
  __shared__ float red4[4];
  __shared__ float redi[4];

  const float* rowbase = inp + (size_t)m * DPER * NFEAT;
  ushort* arowbase = Af16 + (size_t)m * DPER * NFEAT;

  float4 macc0 = {0,0,0,0}, macc1 = {0,0,0,0}, macc2 = {0,0,0,0}, macc3 = {0,0,0,0};
  float r2keep[8];

  #pragma unroll 2
  for (int rr = 0; rr < 8; ++rr) {
    const int d = w * 8 + rr;
    const float* rp = rowbase + (size_t)d * NFEAT + l * 4;
    const float4 v0 = *(const float4*)(rp);
    const float4 v1 = *(const float4*)(rp + 256);
    const float4 v2 = *(const float4*)(rp + 512);
    const float4 v3 = *(const float4*)(rp + 768);
    ushort* ap = arowbase + (size_t)d * NFEAT + l * 4;
    uint2 h;
    h.x = f2h(v0.x) | (f2h(v0.y) << 16); h.y = f2h(v0.z) | (f2h(v0.w) << 16);
    *(uint2*)(ap) = h;
    h.x = f2h(v1.x) | (f2h(v1.y) << 16); h.y = f2h(v1.z) | (f2h(v1.w) << 16);
    *(uint2*)(ap + 256) = h;
    h.x = f2h(v2.x) | (f2h(v2.y) << 16); h.y = f2h(v2.z) | (f2h(v2.w) << 16);
    *(uint2*)(ap + 512) = h;
    h.x = f2h(v3.x) | (f2h(v3.y) << 16); h.y = f2h(v3.z) | (f2h(v3.w) << 16);
    *(uint2*)(ap + 768) = h;
    macc0.x += v0.x; macc0.y += v0.y; macc0.z += v0.z; macc0.w += v0.w;
    macc1.x += v1.x; macc1.y += v1.y; macc1.z += v1.z; macc1.w += v1.w;
    macc2.x += v2.x; macc2.y += v2.y; macc2.z += v2.z; macc2.w += v2.w;
    macc3.x += v3.x; macc3.y += v3.y; macc3.z += v3.z; macc3.w += v3.w;
    float p = v0.x*v0.x + v0.y*v0.y + v0.z*v0.z + v0.w*v0.w
            + v1.x*v1.x + v1.y*v1.y + v1.z*v1.z + v1.w*v1.w
            + v2.x*v2.x + v2.y*v2.y + v2.z*v2.z + v2.w*v2.w
            + v3.x*v3.x + v3.y*v3.y + v3.z*v3.z + v3.w*v3.w;
    #pragma unroll
    for (int off = 32; off; off >>= 1) p += __shfl_down(p, off);
    r2keep[rr] = p;   // full sum valid on lane 0 only
  }
  if (l == 0) {
    float r2s = 0.f;
    #pragma unroll
    for (int rr = 0; rr < 8; ++rr) {
      r2g[m * DPER + w * 8 + rr] = r2keep[rr];
      r2s += r2keep[rr];
    }
    redi[w] = r2s;
  }
  *(float4*)&ldsm[w][0 * 256 + l * 4] = macc0;
  *(float4*)&ldsm[w][1 * 256 + l * 4] = macc1;
  *(float4*)&ldsm[w][2 * 256 + l * 4] = macc2;
  *(float4*)&ldsm[w][3 * 256 + l * 4] = macc3;
  __syncthreads();
  float4 s0 = *(const float4*)&ldsm[0][t * 4];
  float4 s1 = *(const float4*)&ldsm[1][t * 4];
  float4 s2 = *(const float4*)&ldsm[2][t * 4];
  float4 s3 = *(const float4*)&ldsm[3][t * 4];
  const float inv = 1.0f / 32.0f;
  float4 mn;
  mn.x = (s0.x + s1.x + s2.x + s3.x) * inv;
  mn.y = (s0.y + s1.y + s2.y + s3.y) * inv;
  mn.z = (s0.z + s1.z + s2.z + s3.z) * inv;
  mn.w = (s0.w + s1.w + s2.w + s3.w) * inv;
  *(float4*)(means + (size_t)m * NFEAT + t * 4) = mn;
  uint2 bw;
  bw.x = f2h(mn.x) | (f2h(mn.y) << 16);
  bw.y = f2h(mn.z) | (f2h(mn.w) << 16);
  *(uint2*)&Bf16[(size_t)m * NFEAT + t * 4] = bw;
  float sq = mn.x * mn.x + mn.y * mn.y + mn.z * mn.z + mn.w * mn.w;
  #pragma unroll
  for (int off = 32; off; off >>= 1) sq += __shfl_down(sq, off);
  if (l == 0) red4[w] = sq;
  __syncthreads();
  if (t == 0) {
    const float cc = red4[0] + red4[1] + red4[2] + red4[3];
    c2[m] = cc;
    ccls[m] = target[m * DPER];
    percl[m] = (redi[0] + redi[1] + redi[2] + redi[3]) - 32.0f * cc;
    if (m == 0) *wcount = 0;
  }
}

// ---------------- Kernel E: f16 MFMA GEMM, BK=64 dbuf counted-vmcnt ---------
// 128x128x64 tile, 4 waves (2x2), 2x32KB LDS buffers (2 blocks/CU).
// Stage: 8 gload16/wave, lane -> row l>>3, chunk (l&7)^(l>>3) (XOR involution).
// Read: chunk q=kg*4+fq at ch=(q^(fr&7))*8. 16 K-steps, vmcnt(8) counted wait.
__global__ __launch_bounds__(256, 2) void k_gemm(
    const ushort* __restrict__ Af16, const ushort* __restrict__ Bf16,
    const float* __restrict__ c2, const float* __restrict__ r2,
    const float* __restrict__ percl, const int* __restrict__ ccls,
    const int* __restrict__ target,
    float* __restrict__ den_p, float* __restrict__ minv_p,
    float* __restrict__ minv2_p, float* __restrict__ minc_p,
    float* __restrict__ intra_g) {
  __shared__ ushort As[2][GBM * GBK];   // 2 x 16 KiB
  __shared__ ushort Bs[2][GBN * GBK];   // 2 x 16 KiB
  __shared__ float redv[4];
  const int t = threadIdx.x;
  const int l = t & 63, w = t >> 6;
  const int wg = (blockIdx.x & 7) * 64 + (blockIdx.x >> 3);  // bijective (512%8==0)
  const int rowblk = wg >> 2, colblk = wg & 3;
  const int row0 = rowblk * GBM, c0 = colblk * GBN;
  const int wr = w >> 1, wc = w & 1;

  const int sR = l >> 3;            // row within 8-row stage group
  const int sg = (l & 7) ^ sR;      // pre-swizzled source chunk (16B units)
  const ushort* sA = Af16 + (size_t)(row0 + w * 32 + sR) * NFEAT + sg * 8;
  const ushort* sB = Bf16 + (size_t)(c0 + w * 32 + sR) * NFEAT + sg * 8;

  const int fr = l & 15, fq = l >> 4;
  const int swz = fr & 7;

  f32x4 acc[4][4];
  #pragma unroll
  for (int i = 0; i < 4; ++i)
    #pragma unroll
    for (int j = 0; j < 4; ++j) acc[i][j] = (f32x4){0.f, 0.f, 0.f, 0.f};

#define STAGE(bi, ks) do {                                                   \
    _Pragma("unroll") for (int i = 0; i < 4; ++i)                            \
      gload16(sA + (size_t)i * 8 * NFEAT + (ks) * GBK,                       \
              &As[bi][(w * 32 + i * 8) * GBK]);                              \
    _Pragma("unroll") for (int i = 0; i < 4; ++i)                            \
      gload16(sB + (size_t)i * 8 * NFEAT + (ks) * GBK,                       \
              &Bs[bi][(w * 32 + i * 8) * GBK]);                              \
  } while (0)

#define COMPUTE(bi) do {                                                     \
    _Pragma("unroll") for (int kg = 0; kg < 2; ++kg) {                       \
      const int ch = (((kg * 4 + fq) ^ swz) * 8);                            \
      f16x8 a[4], b[4];                                                      \
      _Pragma("unroll") for (int i = 0; i < 4; ++i)                          \
        a[i] = *(const f16x8*)&As[bi][(wr * 64 + i * 16 + fr) * GBK + ch];   \
      _Pragma("unroll") for (int j = 0; j < 4; ++j)                          \
        b[j] = *(const f16x8*)&Bs[bi][(wc * 64 + j * 16 + fr) * GBK + ch];   \
      _Pragma("unroll") for (int i = 0; i < 4; ++i)                          \
        _Pragma("unroll") for (int j = 0; j < 4; ++j)                        \
          acc[i][j] = __builtin_amdgcn_mfma_f32_16x16x32_f16(a[i], b[j],     \
                                                         acc[i][j], 0,0,0);  \
    }                                                                        \
  } while (0)

  STAGE(0, 0);
  #pragma unroll 1
  for (int ks = 0; ks < NFEAT / GBK - 2; ks += 2) {
    STAGE(1, ks + 1);
    asm volatile("s_waitcnt vmcnt(8)" ::: "memory");  // current tile landed, prefetch in flight
    __builtin_amdgcn_s_barrier();
    COMPUTE(0);
    __builtin_amdgcn_s_barrier();
    STAGE(0, ks + 2);
    asm volatile("s_waitcnt vmcnt(8)" ::: "memory");
    __builtin_amdgcn_s_barrier();
    COMPUTE(1);
    __builtin_amdgcn_s_barrier();
  }
  STAGE(1, NFEAT / GBK - 1);
  asm volatile("s_waitcnt vmcnt(8)" ::: "memory");
  __builtin_amdgcn_s_barrier();
  COMPUTE(0);
  __builtin_amdgcn_s_barrier();
  asm volatile("s_waitcnt vmcnt(0)" ::: "memory");
  __builtin_amdgcn_s_barrier();
  COMPUTE(1);
#undef STAGE
#undef COMPUTE

  // ---- vn from percl (every block; deterministic) ----
  float vs = percl[t] + percl[t + 256];
  #pragma unroll
  for (int off = 32; off; off >>= 1) vs += __shfl_down(vs, off);
  if (l == 0) redv[w] = vs;
  __syncthreads();
  const float var = (redv[0] + redv[1] + redv[2] + redv[3]) / (float)(NSAMP - 1);
  const float vn = -1.0f / (2.0f * var * var);

  // ---- fused epilogue ----
  float c2j[4]; int clsj[4], cjv[4];
  #pragma unroll
  for (int j = 0; j < 4; ++j) {
    const int c = c0 + wc * 64 + j * 16 + fr;
    cjv[j] = c;
    c2j[j] = c2[c];
    clsj[j] = ccls[c];
  }
  const int colchunk = colblk * 2 + wc;
  #pragma unroll
  for (int i = 0; i < 4; ++i) {
    const int rbase = row0 + wr * 64 + i * 16 + fq * 4;
    const int cm = rbase >> 5;   // own cluster (same for rows rbase..rbase+3)
    float r2v[4]; int tg[4];
    #pragma unroll
    for (int v = 0; v < 4; ++v) { r2v[v] = r2[rbase + v]; tg[v] = target[rbase + v]; }
    #pragma unroll
    for (int v = 0; v < 4; ++v) {
      float den = 0.f, bv = 3.4e38f, bv2 = 3.4e38f;
      int bc = 1 << 30;
      #pragma unroll
      for (int j = 0; j < 4; ++j) {
        const float cost = r2v[v] + c2j[j] - 2.0f * acc[i][j][v];
        if (clsj[j] != tg[v]) den += __expf(vn * cost);
        if (cjv[j] == cm) intra_g[rbase + v] = cost;   // per-row intra (one lane)
        if (cost < bv) { bv2 = bv; bv = cost; bc = cjv[j]; }
        else if (cost < bv2) { bv2 = cost; }
      }
      #pragma unroll
      for (int off = 1; off < 16; off <<= 1) {
        den += __shfl_xor(den, off);
        const float ov = __shfl_xor(bv, off);
        const float ov2 = __shfl_xor(bv2, off);
        const int oc = __shfl_xor(bc, off);
        const float nb2 = fminf(fminf(bv2, ov2), fmaxf(bv, ov));
        if (ov < bv || (ov == bv && oc < bc)) { bv = ov; bc = oc; }
        bv2 = nb2;
      }
      if (fr == 0) {
        const int idx = colchunk * NSAMP + rbase + v;
        den_p[idx] = den;
        minv_p[idx] = bv;
        minv2_p[idx] = bv2;
        minc_p[idx] = (float)bc;
      }
    }
  }
}

// ---------------- Kernel F2: combine partials (vn from percl) ----------------
__global__ __launch_bounds__(256) void k_fin2(const float* __restrict__ den_p,
                                              const float* __restrict__ minv_p,
                                              const float* __restrict__ minv2_p,
                                              const float* __restrict__ minc_p,
                                              const float* __restrict__ intra_g,
                                              const float* __restrict__ percl,
                                              float* __restrict__ losses,
                                              int* __restrict__ wl,
                                              int* __restrict__ wcount,
                                              unsigned long long* __restrict__ slots) {
  __shared__ float redv[4];
  const int t = threadIdx.x;
  float vs = percl[t] + percl[t + 256];
  #pragma unroll
  for (int off = 32; off; off >>= 1) vs += __shfl_down(vs, off);
  if ((t & 63) == 0) redv[t >> 6] = vs;
  __syncthreads();
  const float var = (redv[0] + redv[1] + redv[2] + redv[3]) / (float)(NSAMP - 1);
  const float vn = -1.0f / (2.0f * var * var);

  const int row = blockIdx.x * 256 + t;
  float den = 0.f, bv = 3.4e38f, bv2 = 3.4e38f, bc = 0.f;
  #pragma unroll
  for (int k = 0; k < NCHUNK; ++k) {
    den += den_p[k * NSAMP + row];
    const float v = minv_p[k * NSAMP + row];
    const float v2 = minv2_p[k * NSAMP + row];
    const float c = minc_p[k * NSAMP + row];
    const float nb2 = fminf(fminf(bv2, v2), fmaxf(bv, v));
    if (v < bv) { bv = v; bc = c; }
    bv2 = nb2;
  }
  const float num = expf(vn * intra_g[row] - ALPHA_C);
  const float ratio = num / (den + EPS_C) + EPS_C;
  float loss = -logf(ratio);
  losses[row] = loss > 0.f ? loss : 0.f;
  if (bv2 - bv < MARGIN_C) {
    slots[row] = 0xFFFFFFFFFFFFFFFFULL;
    int i = atomicAdd(wcount, 1);
    wl[i] = row;
  } else {
    slots[row] = ((unsigned long long)__float_as_uint(bv) << 32) | (unsigned)(int)bc;
  }
}

// ---------------- Kernel G: exact fp32 argmin fixup (parallel chunks) -------
__global__ __launch_bounds__(256) void k_fix(const float* __restrict__ inp,
                                             const float* __restrict__ means,
                                             const float* __restrict__ c2,
                                             const float* __restrict__ r2,
                                             const int* __restrict__ wl,
                                             const int* __restrict__ wcount,
                                             unsigned long long* __restrict__ slots) {
  __shared__ float rbuf[NFEAT];
  const int t = threadIdx.x;
  const int l = t & 63, w = t >> 6;
  const int cnt = *wcount;
  const int chunk = blockIdx.x & 63;
  for (int wi = blockIdx.x >> 6; wi < cnt; wi += gridDim.x >> 6) {
    const int row = wl[wi];
    __syncthreads();
    *(float4*)&rbuf[t * 4] = *(const float4*)(inp + (size_t)row * NFEAT + t * 4);
    __syncthreads();
    float rb[16];
    #pragma unroll
    for (int q = 0; q < 4; ++q) {
      const float4 v = *(const float4*)&rbuf[q * 256 + l * 4];
      rb[q * 4 + 0] = v.x; rb[q * 4 + 1] = v.y;
      rb[q * 4 + 2] = v.z; rb[q * 4 + 3] = v.w;
    }
    const float r2v = r2[row];
    #pragma unroll
    for (int cc = 0; cc < 2; ++cc) {
      const int c = chunk * 8 + w * 2 + cc;
      const float* mp = means + (size_t)c * NFEAT + l * 4;
      float dot = 0.f;
      #pragma unroll
      for (int q = 0; q < 4; ++q) {
        const float4 m4 = *(const float4*)(mp + q * 256);
        dot += m4.x * rb[q * 4 + 0] + m4.y * rb[q * 4 + 1] +
               m4.z * rb[q * 4 + 2] + m4.w * rb[q * 4 + 3];
      }
      #pragma unroll
      for (int off = 32; off; off >>= 1) dot += __shfl_down(dot, off);
      if (l == 0) {
        const float cost = r2v + c2[c] - 2.0f * dot;
        const unsigned long long enc =
            ((unsigned long long)__float_as_uint(cost) << 32) | (unsigned)c;
        atomicMin(&slots[row], enc);
      }
    }
  }
}

// ---------------- Kernel F: preds from slots + total_loss + acc -------------
__global__ __launch_bounds__(256) void k_final(const float* __restrict__ losses,
                                               const unsigned long long* __restrict__ slots,
                                               float* __restrict__ preds,
                                               float* __restrict__ out) {
  const int t = threadIdx.x;
  float s = 0.f, cnt = 0.f;
  for (int i = t; i < NSAMP; i += 256) {
    s += losses[i];
    const int p = (int)(unsigned)(slots[i] & 0xFFFFFFFFULL);
    preds[i] = (float)p;
    cnt += (p == (i >> 5)) ? 1.f : 0.f;
  }
  __shared__ float redS[4], redC[4];
  #pragma unroll
  for (int off = 32; off > 0; off >>= 1) {
    s += __shfl_down(s, off);
    cnt += __shfl_down(cnt, off);
  }
  if ((t & 63) == 0) { redS[t >> 6] = s; redC[t >> 6] = cnt; }
  __syncthreads();
  if (t == 0) {
    out[0] = (redS[0] + redS[1] + redS[2] + redS[3]) / (float)NSAMP;
    out[1 + 2 * NSAMP] = (redC[0] + redC[1] + redC[2] + redC[3]) / (float)NSAMP;
  }
}

extern "C" void kernel_launch(void* const* d_in, const int* in_sizes, int n_in,
                              void* d_out, int out_size, void* d_ws, size_t ws_size,
                              hipStream_t stream) {
  const float* inp = (const float*)d_in[0];
  const int* target = (const int*)d_in[1];
  float* out = (float*)d_out;

  ushort* Af16 = (ushort*)d_ws;                        // 16384*1024 f16 (32 MiB)
  ushort* Bf16 = Af16 + (size_t)NSAMP * NFEAT;         // 512*1024 f16 (1 MiB)
  unsigned long long* slots =
      (unsigned long long*)(Bf16 + (size_t)NCLUST * NFEAT);  // 16384 u64
  float* means = (float*)(slots + NSAMP);              // 512*1024 f32
  float* c2 = means + (size_t)NCLUST * NFEAT;          // 512
  float* r2 = c2 + NCLUST;                             // 16384
  float* intra_g = r2 + NSAMP;                         // 16384 (written by k_gemm)
  float* vn = intra_g + NSAMP;                         // 1 (unused, layout keep)
  float* percl = vn + 1;                               // 512
  int* ccls = (int*)(percl + NCLUST);                  // 512
  float* den_p = (float*)(ccls + NCLUST);              // 8*16384
  float* minv_p = den_p + NCHUNK * NSAMP;              // 8*16384
  float* minv2_p = minv_p + NCHUNK * NSAMP;            // 8*16384
  float* minc_p = minv2_p + NCHUNK * NSAMP;            // 8*16384
  int* wl = (int*)(minc_p + NCHUNK * NSAMP);           // 16384
  int* wcount = wl + NSAMP;                            // 1

  float* losses = out + 1;
  float* preds = out + 1 + NSAMP;

  hipLaunchKernelGGL(k_pre, dim3(NCLUST), dim3(256), 0, stream,
                     inp, target, means, Bf16, Af16, c2, r2, percl, ccls, wcount);
  hipLaunchKernelGGL(k_gemm, dim3(512), dim3(256), 0, stream,
                     Af16, Bf16, c2, r2, percl, ccls, target,
                     den_p, minv_p, minv2_p, minc_p, intra_g);
  hipLaunchKernelGGL(k_fin2, dim3(NSAMP / 256), dim3(256), 0, stream,
                     den_p, minv_p, minv2_p, minc_p, intra_g, percl, losses,
                     wl, wcount, slots);
  hipLaunchKernelGGL(k_fix, dim3(2048), dim3(256), 0, stream,
                     inp, means, c2, r2, wl, wcount, slots);
  hipLaunchKernelGGL(k_final, dim3(1), dim3(256), 0, stream,
                     losses, slots, preds, out);
}